// Round 5
// baseline (2705.747 us; speedup 1.0000x reference)
//
#include <hip/hip_runtime.h>
#include <hip/hip_bf16.h>
#include <stdint.h>

#define B_   128
#define S_   512
#define C_   256
#define DG_  256

// d_out offsets (fp32 elements): outs, pi, sigma, mu, mask
#define OFF_PI   262144
#define OFF_SIG  917504
#define OFF_MU   3538944
#define OFF_MASK 6160384

typedef __hip_bfloat16 bf16;
typedef __bf16 bf16x8 __attribute__((ext_vector_type(8)));
typedef float  f32x4  __attribute__((ext_vector_type(4)));
typedef unsigned int u32;
typedef unsigned int u32x4 __attribute__((ext_vector_type(4)));

// ---- staging in device globals (zero d_ws dependence) ----
__device__ __align__(16) bf16  gWmain[768*256];   // Wih0[:, :256]
__device__ __align__(16) bf16  gWHH0 [768*256];
__device__ __align__(16) bf16  gWIH1 [768*256];
__device__ __align__(16) bf16  gWHH1 [768*256];
__device__ __align__(16) bf16  gWcat [96*512];    // [W_pi; W_sigma; W_mu; 0]
__device__ __align__(16) float gWtail[768*4];     // Wih0[:, 256:260] fp32
__device__ __align__(16) float gSm   [3200];      // small params fp32
__device__ __align__(16) bf16  gHbuf [B_*S_*DG_]; // h1 per (b,t), b-major (32 MB)
__device__ __align__(16) bf16  gH0   [B_*S_*DG_]; // h0 per (t,b), t-major (32 MB)
__device__ __align__(16) float gGi0  [50331648];  // gi0[t][b][768] fp32 (201 MB)
__device__ __align__(16) float gGi1  [50331648];  // gi1[t][b][768] fp32 (201 MB)
__device__ __align__(16) float gPn   [65536*4];   // prenet per (b,t)

// gSm offsets
#define SM_WPRE 0
#define SM_BPRE 16
#define SM_BIH0 20
#define SM_BHH0 788
#define SM_BIH1 1556
#define SM_BHH1 2324
#define SM_BPI  3092
#define SM_BSIG 3102
#define SM_BMU  3142

__device__ __forceinline__ bf16  f2b(float x){ return __float2bfloat16(x); }
__device__ __forceinline__ unsigned short b2u(bf16 x){
    union { bf16 b; unsigned short u; } c; c.b = x; return c.u;
}
__device__ __forceinline__ float sigm(float x){ return 1.f/(1.f + __expf(-x)); }
__device__ __forceinline__ float tanhfast(float x){ return 1.f - 2.f/(__expf(2.f*x) + 1.f); }
__device__ __forceinline__ f32x4 mfma16(bf16x8 a, bf16x8 b, f32x4 c){
    return __builtin_amdgcn_mfma_f32_16x16x32_bf16(a, b, c, 0, 0, 0);
}
__device__ __forceinline__ bf16x8 u2b(u32x4 x){
    union { u32x4 u; bf16x8 b; } c; c.u = x; return c.b;
}
__device__ __forceinline__ bf16x8 cvt8(const float* f){
    float4 a = *reinterpret_cast<const float4*>(f);
    float4 c = *reinterpret_cast<const float4*>(f + 4);
    bf16 o[8] = { f2b(a.x),f2b(a.y),f2b(a.z),f2b(a.w),
                  f2b(c.x),f2b(c.y),f2b(c.z),f2b(c.w) };
    return *reinterpret_cast<bf16x8*>(o);
}

// ---------------------------------------------------------------------------
// ingest: canonicalize fp32 params into device globals + prenet
#define IN_N0 199680
#define IN_N1 396288
#define IN_N2 592896
#define IN_N3 789504
#define IN_N4 838656
#define IN_N5 841838
#define IN_N6 1103982
__global__ __launch_bounds__(256) void k_ingest(
    const float* __restrict__ Wih0, const float* __restrict__ Whh0,
    const float* __restrict__ Wih1, const float* __restrict__ Whh1,
    const float* __restrict__ Wpi, const float* __restrict__ Wsig,
    const float* __restrict__ Wmu,
    const float* __restrict__ Wpre, const float* __restrict__ bpre,
    const float* __restrict__ bih0, const float* __restrict__ bhh0,
    const float* __restrict__ bih1, const float* __restrict__ bhh1,
    const float* __restrict__ bpi, const float* __restrict__ bsig,
    const float* __restrict__ bmu, const float* __restrict__ tgt)
{
    int j = blockIdx.x*256 + threadIdx.x;
    if (j < IN_N0){
        int r = j/260, c = j - r*260;
        float v = Wih0[j];
        if (c < 256) gWmain[r*256 + c] = f2b(v);
        else         gWtail[r*4 + (c-256)] = v;
    } else if (j < IN_N1){
        int k = j - IN_N0; gWHH0[k] = f2b(Whh0[k]);
    } else if (j < IN_N2){
        int k = j - IN_N1; gWIH1[k] = f2b(Wih1[k]);
    } else if (j < IN_N3){
        int k = j - IN_N2; gWHH1[k] = f2b(Whh1[k]);
    } else if (j < IN_N4){
        int k = j - IN_N3; int r = k >> 9, c = k & 511;
        float v = 0.f;
        if      (r < 10) v = Wpi[r*512 + c];
        else if (r < 50) v = Wsig[(r-10)*512 + c];
        else if (r < 90) v = Wmu[(r-50)*512 + c];
        gWcat[k] = f2b(v);
    } else if (j < IN_N5){
        int k = j - IN_N4;
        float v;
        if      (k < 16)   v = Wpre[k];
        else if (k < 20)   v = bpre[k-16];
        else if (k < 788)  v = bih0[k-20];
        else if (k < 1556) v = bhh0[k-788];
        else if (k < 2324) v = bih1[k-1556];
        else if (k < 3092) v = bhh1[k-2324];
        else if (k < 3102) v = bpi[k-3092];
        else if (k < 3142) v = bsig[k-3102];
        else               v = bmu[k-3142];
        gSm[k] = v;
    } else if (j < IN_N6){
        // prenet: pn[m][jj] = bpre[jj] + sum_q Wpre[jj][q]*tgt[m-1][q]  (m = b*512+t)
        int k = j - IN_N5, m = k>>2, jj = k&3, tq = m&511;
        float acc = bpre[jj];
        if (tq){
            const float* pv = tgt + (size_t)(m-1)*4;
            #pragma unroll
            for (int q=0;q<4;q++) acc += Wpre[jj*4+q]*pv[q];
        }
        gPn[m*4+jj] = acc;
    }
}

// ---------------------------------------------------------------------------
// k_gi0: gi0[t][b][n] = (Wih0 @ [enc;prenet])[n] + bih0[n] (+ bhh0[n] folded
// for the r/z gate halves, n<512 — pure-additive, so order-only fp change).
__global__ __launch_bounds__(256) void k_gi0(const float* __restrict__ enc)
{
    const int tid = threadIdx.x, w = tid>>6, lane = tid&63;
    const int col = lane&15, quad = lane>>4;
    const int m0 = blockIdx.x*64 + w*16;

    bf16x8 aF[8];
    #pragma unroll
    for (int kt=0; kt<8; kt++)
        aF[kt] = cvt8(enc + (size_t)(m0+col)*256 + kt*32 + quad*8);

    float4 pnr[4];
    #pragma unroll
    for (int r=0; r<4; r++)
        pnr[r] = *reinterpret_cast<const float4*>(gPn + (size_t)(m0 + quad*4 + r)*4);
    const int mrow = m0 + quad*4;

    for (int nt=0; nt<48; nt++){
        const int n = nt*16 + col;
        f32x4 acc = {0.f,0.f,0.f,0.f};
        #pragma unroll
        for (int kt=0; kt<8; kt++){
            bf16x8 bW = *reinterpret_cast<const bf16x8*>(gWmain + (size_t)n*256 + kt*32 + quad*8);
            acc = mfma16(aF[kt], bW, acc);
        }
        float4 wt = ((const float4*)gWtail)[n];
        float  bi = gSm[SM_BIH0 + n] + ((n < 512) ? gSm[SM_BHH0 + n] : 0.f);
        #pragma unroll
        for (int r=0; r<4; r++){
            int m = mrow + r; int bq = m>>9, tq = m&511;
            float v = acc[r] + bi + wt.x*pnr[r].x + wt.y*pnr[r].y
                              + wt.z*pnr[r].z + wt.w*pnr[r].w;
            gGi0[((size_t)tq*128 + bq)*768 + n] = v;
        }
    }
}

// ---------------------------------------------------------------------------
// k_gi1: gi1[t][b][n] = (Wih1 @ h0[t][b])[n] + bih1[n] (+ bhh1[n] for n<512).
__global__ __launch_bounds__(256) void k_gi1()
{
    const int tid = threadIdx.x, w = tid>>6, lane = tid&63;
    const int col = lane&15, quad = lane>>4;
    const int m0 = blockIdx.x*64 + w*16;

    bf16x8 aF[8];
    #pragma unroll
    for (int kt=0; kt<8; kt++)
        aF[kt] = *reinterpret_cast<const bf16x8*>(gH0 + (size_t)(m0+col)*256 + kt*32 + quad*8);

    for (int nt=0; nt<48; nt++){
        const int n = nt*16 + col;
        f32x4 acc = {0.f,0.f,0.f,0.f};
        #pragma unroll
        for (int kt=0; kt<8; kt++){
            bf16x8 bW = *reinterpret_cast<const bf16x8*>(gWIH1 + (size_t)n*256 + kt*32 + quad*8);
            acc = mfma16(aF[kt], bW, acc);
        }
        float bi = gSm[SM_BIH1 + n] + ((n < 512) ? gSm[SM_BHH1 + n] : 0.f);
        #pragma unroll
        for (int r=0; r<4; r++)
            gGi1[((size_t)(m0 + quad*4 + r))*768 + n] = acc[r] + bi;
    }
}

// ---------------------------------------------------------------------------
// k_rec: sequential ZoneOut-GRU layer. 16 blocks x 256 thr (4 waves,
// 1 wave/SIMD -> 512 unified regs/lane). Block = 8 batches, all 256 dims
// local. Wave w owns q = 4w..4w+3 -> 12 tiles (g=0..2 x qi=0..3), ALL
// register-resident: 8 tiles in AGPR (inline-asm mfma reads "a" directly,
// no accvgpr shuttle - R4's mistake), 4 tiles in VGPR (intrinsic).
// B-operand trick: hv row = col&7 -> batches duplicated across both column
// halves, so every tile's output is valid in all 16 cols; lane half
// (col>>3) gate-processes its q-pair fully in-register. Zero gA LDS.
// Per step per CU: 32 ds_read_b128 + 8 ds_write_b64 only.
__global__ __launch_bounds__(256, 1) void k_rec(int layer)
{
    __shared__ bf16 hv[2][8][272];   // double-buffered h, 8 batches

    const bf16*  __restrict__ W  = layer ? gWHH1 : gWHH0;
    const float* __restrict__ gi = layer ? gGi1  : gGi0;
    const int smOff = layer ? SM_BHH1 : SM_BHH0;
    bf16* __restrict__ hout = layer ? gHbuf : gH0;

    const int tid = threadIdx.x, w = tid>>6, lane = tid&63;
    const int col = lane&15, quad = lane>>4;
    const int bg8 = blockIdx.x*8;
    const int c8 = col&7, hsel = col>>3;

    for (int i=tid; i<2*8*272; i+=256) (&hv[0][0][0])[i] = f2b(0.f);

    // ---- weight tiles j = qi*3+g (q = 4w+qi): j<8 AGPR, j>=8 VGPR ----
    u32x4 wA[8][8];
    #pragma unroll
    for (int j=0;j<8;j++){
        const int qi = j/3, g = j - qi*3;
        const bf16* Wr = W + ((size_t)(g*256 + (4*w+qi)*16 + col))*256;
        #pragma unroll
        for (int kt=0;kt<8;kt++){
            wA[j][kt] = *reinterpret_cast<const u32x4*>(Wr + kt*32 + quad*8);
            asm volatile("" : "+a"(wA[j][kt]));   // park in AGPR, no remat
        }
    }
    u32x4 wV[4][8];
    #pragma unroll
    for (int j=0;j<4;j++){
        const int jj = 8+j, qi = jj/3, g = jj - qi*3;
        const bf16* Wr = W + ((size_t)(g*256 + (4*w+qi)*16 + col))*256;
        #pragma unroll
        for (int kt=0;kt<8;kt++){
            wV[j][kt] = *reinterpret_cast<const u32x4*>(Wr + kt*32 + quad*8);
            asm volatile("" : "+v"(wV[j][kt]));   // pin in arch VGPR
        }
    }

    // ---- per-lane gate geometry: batch c8, q-pair (4w+2*hsel, +1) ----
    const int q0 = 4*w + 2*hsel, q1 = q0 + 1;
    const int d0 = q0*16 + quad*4, d1 = q1*16 + quad*4;
    float4 bhn0 = *reinterpret_cast<const float4*>(&gSm[smOff + 512 + d0]);
    float4 bhn1 = *reinterpret_cast<const float4*>(&gSm[smOff + 512 + d1]);
    const float* gib = gi + (size_t)(bg8 + c8)*768;
    bf16 *hop0, *hop1; size_t hstep;
    if (layer){
        hop0 = hout + ((size_t)(bg8+c8)*512)*256 + d0;
        hop1 = hout + ((size_t)(bg8+c8)*512)*256 + d1;
        hstep = 256;                      // b-major (gHbuf)
    } else {
        hop0 = hout + (size_t)(bg8+c8)*256 + d0;
        hop1 = hout + (size_t)(bg8+c8)*256 + d1;
        hstep = 128*256;                  // t-major (gH0)
    }
    float h0r[4] = {0.f,0.f,0.f,0.f}, h1r[4] = {0.f,0.f,0.f,0.f};

    __syncthreads();

    #pragma unroll 1
    for (int t=0; t<S_; t++){
        // ---- issue gi(t) loads early; consumed after MFMA (~500cy cover) ----
        const float* gp = gib + (size_t)t*98304;   // 128*768
        float4 gr0 = *reinterpret_cast<const float4*>(gp + d0);
        float4 gz0 = *reinterpret_cast<const float4*>(gp + 256 + d0);
        float4 gn0 = *reinterpret_cast<const float4*>(gp + 512 + d0);
        float4 gr1 = *reinterpret_cast<const float4*>(gp + d1);
        float4 gz1 = *reinterpret_cast<const float4*>(gp + 256 + d1);
        float4 gn1 = *reinterpret_cast<const float4*>(gp + 512 + d1);

        f32x4 acc[12];
        #pragma unroll
        for (int j=0;j<12;j++) acc[j] = f32x4{0.f,0.f,0.f,0.f};
        asm volatile("s_nop 2" :::);   // VALU-write -> MFMA-read hazard guard

        const bf16* hrow = &hv[t&1][c8][0];
        #pragma unroll
        for (int kt=0;kt<8;kt++){
            u32x4 hbu = *reinterpret_cast<const u32x4*>(hrow + kt*32 + quad*8);
            #pragma unroll
            for (int j=0;j<8;j++)
                asm volatile("v_mfma_f32_16x16x32_bf16 %0, %1, %2, %0"
                             : "+v"(acc[j]) : "a"(wA[j][kt]), "v"(hbu));
            bf16x8 hbb = u2b(hbu);
            #pragma unroll
            for (int j=0;j<4;j++)
                acc[8+j] = mfma16(u2b(wV[j][kt]), hbb, acc[8+j]);
        }
        asm volatile("s_nop 7\n\ts_nop 7" :::);   // MFMA-write -> VALU-read guard

        // ---- select this lane-half's q-pair accumulators (literal idx) ----
        f32x4 aR0 = hsel ? acc[6]  : acc[0];
        f32x4 aZ0 = hsel ? acc[7]  : acc[1];
        f32x4 aN0 = hsel ? acc[8]  : acc[2];
        f32x4 aR1 = hsel ? acc[9]  : acc[3];
        f32x4 aZ1 = hsel ? acc[10] : acc[4];
        f32x4 aN1 = hsel ? acc[11] : acc[5];

        // ---- gates (bit-identical formula to validated R4) ----
        float hp0[4], hp1[4];
        #pragma unroll
        for (int r=0;r<4;r++){
            float rr = sigm(((const float*)&gr0)[r] + aR0[r]);
            float zz = sigm(((const float*)&gz0)[r] + aZ0[r]);
            float nn = tanhfast(((const float*)&gn0)[r] + rr*(aN0[r] + ((const float*)&bhn0)[r]));
            float h  = h0r[r];
            float v  = 0.1f*h + 0.9f*((1.f-zz)*nn + zz*h);
            h0r[r] = v; hp0[r] = v;
        }
        #pragma unroll
        for (int r=0;r<4;r++){
            float rr = sigm(((const float*)&gr1)[r] + aR1[r]);
            float zz = sigm(((const float*)&gz1)[r] + aZ1[r]);
            float nn = tanhfast(((const float*)&gn1)[r] + rr*(aN1[r] + ((const float*)&bhn1)[r]));
            float h  = h1r[r];
            float v  = 0.1f*h + 0.9f*((1.f-zz)*nn + zz*h);
            h1r[r] = v; hp1[r] = v;
        }

        // ---- pack bf16, write next-step LDS buffer + global H ----
        uint2 u0, u1;
        u0.x = (u32)b2u(f2b(hp0[0])) | ((u32)b2u(f2b(hp0[1]))<<16);
        u0.y = (u32)b2u(f2b(hp0[2])) | ((u32)b2u(f2b(hp0[3]))<<16);
        u1.x = (u32)b2u(f2b(hp1[0])) | ((u32)b2u(f2b(hp1[1]))<<16);
        u1.y = (u32)b2u(f2b(hp1[2])) | ((u32)b2u(f2b(hp1[3]))<<16);
        *reinterpret_cast<uint2*>(&hv[(t&1)^1][c8][d0]) = u0;
        *reinterpret_cast<uint2*>(&hv[(t&1)^1][c8][d1]) = u1;
        *reinterpret_cast<uint2*>(hop0) = u0;  hop0 += hstep;
        *reinterpret_cast<uint2*>(hop1) = u1;  hop1 += hstep;

        // ---- one barrier/step: LDS visible, NO vmcnt drain ----
        asm volatile("s_waitcnt lgkmcnt(0)" ::: "memory");
        __builtin_amdgcn_sched_barrier(0);
        __builtin_amdgcn_s_barrier();
        __builtin_amdgcn_sched_barrier(0);
    }
}

// ---------------------------------------------------------------------------
// Fused projection + heads: 512 blocks x 128 rows. [H|enc]@Wcat^T -> LDS ->
// softmax/elu/mu, fp32 stores.
__global__ __launch_bounds__(256) void k_proj(
    const float* __restrict__ enc, float* __restrict__ dout)
{
    __shared__ float st[128][100];
    const int tid = threadIdx.x, w = tid>>6, lane = tid&63;
    const int col = lane&15, quad = lane>>4;
    const int Mb = blockIdx.x*128;
    const int M0 = Mb + w*32;

    f32x4 acc[2][6];
    #pragma unroll
    for (int mt=0; mt<2; mt++)
        #pragma unroll
        for (int nt=0; nt<6; nt++) acc[mt][nt] = f32x4{0.f,0.f,0.f,0.f};

    #pragma unroll
    for (int kt=0; kt<16; kt++){
        bf16x8 a0, a1;
        if (kt < 8){
            a0 = *reinterpret_cast<const bf16x8*>(gHbuf + (size_t)(M0 +      col)*DG_ + kt*32 + quad*8);
            a1 = *reinterpret_cast<const bf16x8*>(gHbuf + (size_t)(M0 + 16 + col)*DG_ + kt*32 + quad*8);
        } else {
            a0 = cvt8(enc + (size_t)(M0 +      col)*C_ + (kt-8)*32 + quad*8);
            a1 = cvt8(enc + (size_t)(M0 + 16 + col)*C_ + (kt-8)*32 + quad*8);
        }
        #pragma unroll
        for (int nt=0; nt<6; nt++){
            bf16x8 b = *reinterpret_cast<const bf16x8*>(gWcat + (size_t)(nt*16 + col)*512 + kt*32 + quad*8);
            acc[0][nt] = mfma16(a0, b, acc[0][nt]);
            acc[1][nt] = mfma16(a1, b, acc[1][nt]);
        }
    }
    #pragma unroll
    for (int nt=0; nt<6; nt++)
        #pragma unroll
        for (int mt=0; mt<2; mt++)
            #pragma unroll
            for (int r=0; r<4; r++)
                st[w*32 + mt*16 + quad*4 + r][nt*16 + col] = acc[mt][nt][r];
    __syncthreads();

    if (tid < 128){
        const float* v = st[tid];
        const size_t m = (size_t)Mb + tid;
        float x[10], mx = -1e30f;
        #pragma unroll
        for (int g=0; g<10; g++){ x[g] = v[g] + gSm[SM_BPI+g]; mx = fmaxf(mx, x[g]); }
        float sum = 0.f;
        #pragma unroll
        for (int g=0; g<10; g++){ x[g] = __expf(x[g]-mx); sum += x[g]; }
        float inv = 1.f/sum;
        #pragma unroll
        for (int g=0; g<10; g++)
            dout[OFF_PI + m*10 + g] = x[g]*inv;
        #pragma unroll
        for (int i=0; i<40; i++){
            float s = v[10+i] + gSm[SM_BSIG+i];
            dout[OFF_SIG + m*40 + i] = (s > 0.f) ? (s + 1.f) : __expf(s);
        }
        #pragma unroll
        for (int i=0; i<40; i++)
            dout[OFF_MU + m*40 + i] = v[50+i] + gSm[SM_BMU+i];
    }
}

// ---------------------------------------------------------------------------
// blocks 0..255: outs = fp32 copy of tgt; blocks 256..383: mask
__global__ __launch_bounds__(256) void k_misc(const float* __restrict__ tgt,
    const int* __restrict__ dur, float* __restrict__ dout)
{
    if (blockIdx.x < 256){
        int i = blockIdx.x*256 + threadIdx.x;
        ((float4*)dout)[i] = ((const float4*)tgt)[i];
    } else {
        __shared__ int red[256];
        int b = blockIdx.x - 256;
        int c = 0;
        for (int s = threadIdx.x; s < S_; s += 256) c += (dur[b*S_ + s] > 0) ? 1 : 0;
        red[threadIdx.x] = c;
        __syncthreads();
        for (int off=128; off>0; off>>=1){
            if (threadIdx.x < off) red[threadIdx.x] += red[threadIdx.x+off];
            __syncthreads();
        }
        int snt = red[0];
        for (int s = threadIdx.x; s < S_; s += 256)
            dout[OFF_MASK + (size_t)b*S_ + s] = (s >= snt) ? 1.f : 0.f;
    }
}

// ---------------------------------------------------------------------------
extern "C" void kernel_launch(void* const* d_in, const int* in_sizes, int n_in,
                              void* d_out, int out_size, void* d_ws, size_t ws_size,
                              hipStream_t stream)
{
    (void)d_ws; (void)ws_size;
    const float* enc  = (const float*)d_in[0];
    const float* tgt  = (const float*)d_in[1];
    const int*   dur  = (const int*)  d_in[2];
    const float* Wpre = (const float*)d_in[3];
    const float* bpre = (const float*)d_in[4];
    const float* Wih0 = (const float*)d_in[5];
    const float* Whh0 = (const float*)d_in[6];
    const float* bih0 = (const float*)d_in[7];
    const float* bhh0 = (const float*)d_in[8];
    const float* Wih1 = (const float*)d_in[9];
    const float* Whh1 = (const float*)d_in[10];
    const float* bih1 = (const float*)d_in[11];
    const float* bhh1 = (const float*)d_in[12];
    const float* Wpi  = (const float*)d_in[13];
    const float* bpi  = (const float*)d_in[14];
    const float* Wsig = (const float*)d_in[15];
    const float* bsig = (const float*)d_in[16];
    const float* Wmu  = (const float*)d_in[17];
    const float* bmu  = (const float*)d_in[18];
    float* dout = (float*)d_out;

    hipLaunchKernelGGL(k_ingest, dim3(4313), dim3(256), 0, stream,
                       Wih0, Whh0, Wih1, Whh1, Wpi, Wsig, Wmu,
                       Wpre, bpre, bih0, bhh0, bih1, bhh1, bpi, bsig, bmu, tgt);
    hipLaunchKernelGGL(k_gi0,  dim3(1024), dim3(256), 0, stream, enc);
    hipLaunchKernelGGL(k_rec,  dim3(16),   dim3(256), 0, stream, 0);
    hipLaunchKernelGGL(k_gi1,  dim3(1024), dim3(256), 0, stream);
    hipLaunchKernelGGL(k_rec,  dim3(16),   dim3(256), 0, stream, 1);
    hipLaunchKernelGGL(k_proj, dim3(512),  dim3(256), 0, stream, enc, dout);
    hipLaunchKernelGGL(k_misc, dim3(384),  dim3(256), 0, stream, tgt, dur, dout);
}

// Round 6
// 1981.641 us; speedup vs baseline: 1.3654x; 1.3654x over previous
//
#include <hip/hip_runtime.h>
#include <hip/hip_bf16.h>
#include <stdint.h>

#define B_   128
#define S_   512
#define C_   256
#define DG_  256

// d_out offsets (fp32 elements): outs, pi, sigma, mu, mask
#define OFF_PI   262144
#define OFF_SIG  917504
#define OFF_MU   3538944
#define OFF_MASK 6160384

typedef __hip_bfloat16 bf16;
typedef __bf16 bf16x8 __attribute__((ext_vector_type(8)));
typedef float  f32x4  __attribute__((ext_vector_type(4)));
typedef unsigned int u32;
typedef unsigned int u32x4 __attribute__((ext_vector_type(4)));

// ---- staging in device globals (zero d_ws dependence) ----
__device__ __align__(16) bf16  gWmain[768*256];   // Wih0[:, :256]
__device__ __align__(16) bf16  gWHH0 [768*256];
__device__ __align__(16) bf16  gWIH1 [768*256];
__device__ __align__(16) bf16  gWHH1 [768*256];
__device__ __align__(16) bf16  gWcat [96*512];    // [W_pi; W_sigma; W_mu; 0]
__device__ __align__(16) float gWtail[768*4];     // Wih0[:, 256:260] fp32
__device__ __align__(16) float gSm   [3200];      // small params fp32
__device__ __align__(16) bf16  gHbuf [B_*S_*DG_]; // h1 per (b,t), b-major (32 MB)
__device__ __align__(16) bf16  gH0   [B_*S_*DG_]; // h0 per (t,b), t-major (32 MB)
__device__ __align__(16) float gGi0  [50331648];  // gi0[t][b][768] fp32 (201 MB)
__device__ __align__(16) float gGi1  [50331648];  // gi1[t][b][768] fp32 (201 MB)
__device__ __align__(16) float gPn   [65536*4];   // prenet per (b,t)

// gSm offsets
#define SM_WPRE 0
#define SM_BPRE 16
#define SM_BIH0 20
#define SM_BHH0 788
#define SM_BIH1 1556
#define SM_BHH1 2324
#define SM_BPI  3092
#define SM_BSIG 3102
#define SM_BMU  3142

__device__ __forceinline__ bf16  f2b(float x){ return __float2bfloat16(x); }
__device__ __forceinline__ unsigned short b2u(bf16 x){
    union { bf16 b; unsigned short u; } c; c.b = x; return c.u;
}
__device__ __forceinline__ float sigm(float x){ return 1.f/(1.f + __expf(-x)); }
__device__ __forceinline__ float tanhfast(float x){ return 1.f - 2.f/(__expf(2.f*x) + 1.f); }
__device__ __forceinline__ float rcp_fast(float x){
    float r; asm("v_rcp_f32 %0, %1" : "=v"(r) : "v"(x)); return r;
}
__device__ __forceinline__ u32 cvtpk_bf16(float lo, float hi){
    u32 r; asm("v_cvt_pk_bf16_f32 %0, %1, %2" : "=v"(r) : "v"(lo), "v"(hi)); return r;
}
__device__ __forceinline__ f32x4 mfma16(bf16x8 a, bf16x8 b, f32x4 c){
    return __builtin_amdgcn_mfma_f32_16x16x32_bf16(a, b, c, 0, 0, 0);
}
__device__ __forceinline__ bf16x8 u2b(u32x4 x){
    union { u32x4 u; bf16x8 b; } c; c.u = x; return c.b;
}
__device__ __forceinline__ bf16x8 cvt8(const float* f){
    float4 a = *reinterpret_cast<const float4*>(f);
    float4 c = *reinterpret_cast<const float4*>(f + 4);
    bf16 o[8] = { f2b(a.x),f2b(a.y),f2b(a.z),f2b(a.w),
                  f2b(c.x),f2b(c.y),f2b(c.z),f2b(c.w) };
    return *reinterpret_cast<bf16x8*>(o);
}

// ---------------------------------------------------------------------------
// ingest: canonicalize fp32 params into device globals + prenet
#define IN_N0 199680
#define IN_N1 396288
#define IN_N2 592896
#define IN_N3 789504
#define IN_N4 838656
#define IN_N5 841838
#define IN_N6 1103982
__global__ __launch_bounds__(256) void k_ingest(
    const float* __restrict__ Wih0, const float* __restrict__ Whh0,
    const float* __restrict__ Wih1, const float* __restrict__ Whh1,
    const float* __restrict__ Wpi, const float* __restrict__ Wsig,
    const float* __restrict__ Wmu,
    const float* __restrict__ Wpre, const float* __restrict__ bpre,
    const float* __restrict__ bih0, const float* __restrict__ bhh0,
    const float* __restrict__ bih1, const float* __restrict__ bhh1,
    const float* __restrict__ bpi, const float* __restrict__ bsig,
    const float* __restrict__ bmu, const float* __restrict__ tgt)
{
    int j = blockIdx.x*256 + threadIdx.x;
    if (j < IN_N0){
        int r = j/260, c = j - r*260;
        float v = Wih0[j];
        if (c < 256) gWmain[r*256 + c] = f2b(v);
        else         gWtail[r*4 + (c-256)] = v;
    } else if (j < IN_N1){
        int k = j - IN_N0; gWHH0[k] = f2b(Whh0[k]);
    } else if (j < IN_N2){
        int k = j - IN_N1; gWIH1[k] = f2b(Wih1[k]);
    } else if (j < IN_N3){
        int k = j - IN_N2; gWHH1[k] = f2b(Whh1[k]);
    } else if (j < IN_N4){
        int k = j - IN_N3; int r = k >> 9, c = k & 511;
        float v = 0.f;
        if      (r < 10) v = Wpi[r*512 + c];
        else if (r < 50) v = Wsig[(r-10)*512 + c];
        else if (r < 90) v = Wmu[(r-50)*512 + c];
        gWcat[k] = f2b(v);
    } else if (j < IN_N5){
        int k = j - IN_N4;
        float v;
        if      (k < 16)   v = Wpre[k];
        else if (k < 20)   v = bpre[k-16];
        else if (k < 788)  v = bih0[k-20];
        else if (k < 1556) v = bhh0[k-788];
        else if (k < 2324) v = bih1[k-1556];
        else if (k < 3092) v = bhh1[k-2324];
        else if (k < 3102) v = bpi[k-3092];
        else if (k < 3142) v = bsig[k-3102];
        else               v = bmu[k-3142];
        gSm[k] = v;
    } else if (j < IN_N6){
        // prenet: pn[m][jj] = bpre[jj] + sum_q Wpre[jj][q]*tgt[m-1][q]  (m = b*512+t)
        int k = j - IN_N5, m = k>>2, jj = k&3, tq = m&511;
        float acc = bpre[jj];
        if (tq){
            const float* pv = tgt + (size_t)(m-1)*4;
            #pragma unroll
            for (int q=0;q<4;q++) acc += Wpre[jj*4+q]*pv[q];
        }
        gPn[m*4+jj] = acc;
    }
}

// ---------------------------------------------------------------------------
// k_gi0: gi0[t][b][n] = (Wih0 @ [enc;prenet])[n] + bih0[n] (+ bhh0[n] folded
// for the r/z gate halves, n<512 — pure-additive, so order-only fp change).
__global__ __launch_bounds__(256) void k_gi0(const float* __restrict__ enc)
{
    const int tid = threadIdx.x, w = tid>>6, lane = tid&63;
    const int col = lane&15, quad = lane>>4;
    const int m0 = blockIdx.x*64 + w*16;

    bf16x8 aF[8];
    #pragma unroll
    for (int kt=0; kt<8; kt++)
        aF[kt] = cvt8(enc + (size_t)(m0+col)*256 + kt*32 + quad*8);

    float4 pnr[4];
    #pragma unroll
    for (int r=0; r<4; r++)
        pnr[r] = *reinterpret_cast<const float4*>(gPn + (size_t)(m0 + quad*4 + r)*4);
    const int mrow = m0 + quad*4;

    for (int nt=0; nt<48; nt++){
        const int n = nt*16 + col;
        f32x4 acc = {0.f,0.f,0.f,0.f};
        #pragma unroll
        for (int kt=0; kt<8; kt++){
            bf16x8 bW = *reinterpret_cast<const bf16x8*>(gWmain + (size_t)n*256 + kt*32 + quad*8);
            acc = mfma16(aF[kt], bW, acc);
        }
        float4 wt = ((const float4*)gWtail)[n];
        float  bi = gSm[SM_BIH0 + n] + ((n < 512) ? gSm[SM_BHH0 + n] : 0.f);
        #pragma unroll
        for (int r=0; r<4; r++){
            int m = mrow + r; int bq = m>>9, tq = m&511;
            float v = acc[r] + bi + wt.x*pnr[r].x + wt.y*pnr[r].y
                              + wt.z*pnr[r].z + wt.w*pnr[r].w;
            gGi0[((size_t)tq*128 + bq)*768 + n] = v;
        }
    }
}

// ---------------------------------------------------------------------------
// k_gi1: gi1[t][b][n] = (Wih1 @ h0[t][b])[n] + bih1[n] (+ bhh1[n] for n<512).
__global__ __launch_bounds__(256) void k_gi1()
{
    const int tid = threadIdx.x, w = tid>>6, lane = tid&63;
    const int col = lane&15, quad = lane>>4;
    const int m0 = blockIdx.x*64 + w*16;

    bf16x8 aF[8];
    #pragma unroll
    for (int kt=0; kt<8; kt++)
        aF[kt] = *reinterpret_cast<const bf16x8*>(gH0 + (size_t)(m0+col)*256 + kt*32 + quad*8);

    for (int nt=0; nt<48; nt++){
        const int n = nt*16 + col;
        f32x4 acc = {0.f,0.f,0.f,0.f};
        #pragma unroll
        for (int kt=0; kt<8; kt++){
            bf16x8 bW = *reinterpret_cast<const bf16x8*>(gWIH1 + (size_t)n*256 + kt*32 + quad*8);
            acc = mfma16(aF[kt], bW, acc);
        }
        float bi = gSm[SM_BIH1 + n] + ((n < 512) ? gSm[SM_BHH1 + n] : 0.f);
        #pragma unroll
        for (int r=0; r<4; r++)
            gGi1[((size_t)(m0 + quad*4 + r))*768 + n] = acc[r] + bi;
    }
}

// ---------------------------------------------------------------------------
// k_rec: sequential ZoneOut-GRU layer. 32 blocks x 256 thr (4 waves,
// 1 wave/SIMD -> 512 unified regs/lane). Block = 4 batches. Wave w owns
// q = 4w..4w+3 -> 12 tiles, ALL register-resident (8 AGPR via asm mfma "a",
// 4 VGPR via intrinsic). B-operand: hv row = col&3 (batches duplicated 4x
// across cols); lane (col&3, col>>2) gate-processes ONE (batch, q): 4 rows.
// vs R5: half the gate VALU & gi loads per thread (R5's bottleneck:
// no-fast-math v_div sequences ~15 VALU per sigmoid). Gates now use
// v_rcp_f32 approx (<=1ulp) + v_cvt_pk_bf16_f32 pack. gi double-buffered
// across steps in regs (gc/gn) -> zero vmcnt stall.
__global__ __launch_bounds__(256, 1) void k_rec(int layer)
{
    __shared__ bf16 hv[2][4][272];   // double-buffered h, 4 batches

    const bf16*  __restrict__ W  = layer ? gWHH1 : gWHH0;
    const float* __restrict__ gi = layer ? gGi1  : gGi0;
    const int smOff = layer ? SM_BHH1 : SM_BHH0;
    bf16* __restrict__ hout = layer ? gHbuf : gH0;

    const int tid = threadIdx.x, w = tid>>6, lane = tid&63;
    const int col = lane&15, quad = lane>>4;
    const int bg4 = blockIdx.x*4;
    const int c4 = col&3, qsel = col>>2;

    for (int i=tid; i<2*4*272; i+=256) (&hv[0][0][0])[i] = f2b(0.f);

    // ---- weight tiles j = qi*3+g (q = 4w+qi): j<8 AGPR, j>=8 VGPR ----
    u32x4 wA[8][8];
    #pragma unroll
    for (int j=0;j<8;j++){
        const int qi = j/3, g = j - qi*3;
        const bf16* Wr = W + ((size_t)(g*256 + (4*w+qi)*16 + col))*256;
        #pragma unroll
        for (int kt=0;kt<8;kt++){
            wA[j][kt] = *reinterpret_cast<const u32x4*>(Wr + kt*32 + quad*8);
            asm volatile("" : "+a"(wA[j][kt]));   // park in AGPR, no remat
        }
    }
    u32x4 wV[4][8];
    #pragma unroll
    for (int j=0;j<4;j++){
        const int jj = 8+j, qi = jj/3, g = jj - qi*3;
        const bf16* Wr = W + ((size_t)(g*256 + (4*w+qi)*16 + col))*256;
        #pragma unroll
        for (int kt=0;kt<8;kt++){
            wV[j][kt] = *reinterpret_cast<const u32x4*>(Wr + kt*32 + quad*8);
            asm volatile("" : "+v"(wV[j][kt]));   // pin in arch VGPR
        }
    }

    // ---- per-lane gate geometry: batch c4, q = 4w+qsel, 4 rows ----
    const int q = 4*w + qsel;
    const int d = q*16 + quad*4;
    float4 bhn = *reinterpret_cast<const float4*>(&gSm[smOff + 512 + d]);
    const float* gib = gi + (size_t)(bg4 + c4)*768 + d;
    bf16* hop; size_t hstep;
    if (layer){ hop = hout + ((size_t)(bg4+c4)*512)*256 + d; hstep = 256; }      // b-major
    else      { hop = hout + (size_t)(bg4+c4)*256 + d;       hstep = 128*256; }  // t-major
    float hreg[4] = {0.f,0.f,0.f,0.f};

    // ---- prologue: gi(0) ----
    float4 gr = *reinterpret_cast<const float4*>(gib);
    float4 gz = *reinterpret_cast<const float4*>(gib + 256);
    float4 gn = *reinterpret_cast<const float4*>(gib + 512);

    __syncthreads();

    #pragma unroll 1
    for (int t=0; t<S_; t++){
        // ---- issue gi(t+1) loads now; consumed next step (full-step cover) ----
        float4 pr, pz, pnx;
        if (t+1 < S_){
            const float* gq = gib + (size_t)(t+1)*98304;   // 128*768
            pr  = *reinterpret_cast<const float4*>(gq);
            pz  = *reinterpret_cast<const float4*>(gq + 256);
            pnx = *reinterpret_cast<const float4*>(gq + 512);
        }

        f32x4 acc[12];
        #pragma unroll
        for (int j=0;j<12;j++) acc[j] = f32x4{0.f,0.f,0.f,0.f};
        asm volatile("s_nop 2" :::);   // VALU-write -> MFMA-read hazard guard

        const bf16* hrow = &hv[t&1][c4][0];
        #pragma unroll
        for (int kt=0;kt<8;kt++){
            u32x4 hbu = *reinterpret_cast<const u32x4*>(hrow + kt*32 + quad*8);
            #pragma unroll
            for (int j=0;j<8;j++)
                asm volatile("v_mfma_f32_16x16x32_bf16 %0, %1, %2, %0"
                             : "+v"(acc[j]) : "a"(wA[j][kt]), "v"(hbu));
            bf16x8 hbb = u2b(hbu);
            #pragma unroll
            for (int j=0;j<4;j++)
                acc[8+j] = mfma16(u2b(wV[j][kt]), hbb, acc[8+j]);
        }
        asm volatile("s_nop 7\n\ts_nop 7" :::);   // MFMA-write -> VALU-read guard

        // ---- select this lane's q accumulators (literal idx) ----
        f32x4 aR = (qsel==0) ? acc[0] : (qsel==1) ? acc[3] : (qsel==2) ? acc[6] : acc[9];
        f32x4 aZ = (qsel==0) ? acc[1] : (qsel==1) ? acc[4] : (qsel==2) ? acc[7] : acc[10];
        f32x4 aN = (qsel==0) ? acc[2] : (qsel==1) ? acc[5] : (qsel==2) ? acc[8] : acc[11];

        // ---- gates (same formula; rcp-approx for the divisions) ----
        float hp[4];
        #pragma unroll
        for (int r=0;r<4;r++){
            float rr = rcp_fast(1.f + __expf(-(((const float*)&gr)[r] + aR[r])));
            float zz = rcp_fast(1.f + __expf(-(((const float*)&gz)[r] + aZ[r])));
            float xn = ((const float*)&gn)[r] + rr*(aN[r] + ((const float*)&bhn)[r]);
            float nn = 1.f - 2.f*rcp_fast(__expf(2.f*xn) + 1.f);
            float h  = hreg[r];
            float v  = 0.1f*h + 0.9f*((1.f-zz)*nn + zz*h);
            hreg[r] = v; hp[r] = v;
        }

        // ---- pack bf16 (v_cvt_pk: lo=src0, RNE), write LDS + global H ----
        uint2 u;
        u.x = cvtpk_bf16(hp[0], hp[1]);
        u.y = cvtpk_bf16(hp[2], hp[3]);
        *reinterpret_cast<uint2*>(&hv[(t&1)^1][c4][d]) = u;
        *reinterpret_cast<uint2*>(hop) = u;  hop += hstep;

        gr = pr; gz = pz; gn = pnx;

        // ---- one barrier/step: LDS visible, NO vmcnt drain ----
        asm volatile("s_waitcnt lgkmcnt(0)" ::: "memory");
        __builtin_amdgcn_sched_barrier(0);
        __builtin_amdgcn_s_barrier();
        __builtin_amdgcn_sched_barrier(0);
    }
}

// ---------------------------------------------------------------------------
// Fused projection + heads: 512 blocks x 128 rows. [H|enc]@Wcat^T -> LDS ->
// softmax/elu/mu, fp32 stores.
__global__ __launch_bounds__(256) void k_proj(
    const float* __restrict__ enc, float* __restrict__ dout)
{
    __shared__ float st[128][100];
    const int tid = threadIdx.x, w = tid>>6, lane = tid&63;
    const int col = lane&15, quad = lane>>4;
    const int Mb = blockIdx.x*128;
    const int M0 = Mb + w*32;

    f32x4 acc[2][6];
    #pragma unroll
    for (int mt=0; mt<2; mt++)
        #pragma unroll
        for (int nt=0; nt<6; nt++) acc[mt][nt] = f32x4{0.f,0.f,0.f,0.f};

    #pragma unroll
    for (int kt=0; kt<16; kt++){
        bf16x8 a0, a1;
        if (kt < 8){
            a0 = *reinterpret_cast<const bf16x8*>(gHbuf + (size_t)(M0 +      col)*DG_ + kt*32 + quad*8);
            a1 = *reinterpret_cast<const bf16x8*>(gHbuf + (size_t)(M0 + 16 + col)*DG_ + kt*32 + quad*8);
        } else {
            a0 = cvt8(enc + (size_t)(M0 +      col)*C_ + (kt-8)*32 + quad*8);
            a1 = cvt8(enc + (size_t)(M0 + 16 + col)*C_ + (kt-8)*32 + quad*8);
        }
        #pragma unroll
        for (int nt=0; nt<6; nt++){
            bf16x8 b = *reinterpret_cast<const bf16x8*>(gWcat + (size_t)(nt*16 + col)*512 + kt*32 + quad*8);
            acc[0][nt] = mfma16(a0, b, acc[0][nt]);
            acc[1][nt] = mfma16(a1, b, acc[1][nt]);
        }
    }
    #pragma unroll
    for (int nt=0; nt<6; nt++)
        #pragma unroll
        for (int mt=0; mt<2; mt++)
            #pragma unroll
            for (int r=0; r<4; r++)
                st[w*32 + mt*16 + quad*4 + r][nt*16 + col] = acc[mt][nt][r];
    __syncthreads();

    if (tid < 128){
        const float* v = st[tid];
        const size_t m = (size_t)Mb + tid;
        float x[10], mx = -1e30f;
        #pragma unroll
        for (int g=0; g<10; g++){ x[g] = v[g] + gSm[SM_BPI+g]; mx = fmaxf(mx, x[g]); }
        float sum = 0.f;
        #pragma unroll
        for (int g=0; g<10; g++){ x[g] = __expf(x[g]-mx); sum += x[g]; }
        float inv = 1.f/sum;
        #pragma unroll
        for (int g=0; g<10; g++)
            dout[OFF_PI + m*10 + g] = x[g]*inv;
        #pragma unroll
        for (int i=0; i<40; i++){
            float s = v[10+i] + gSm[SM_BSIG+i];
            dout[OFF_SIG + m*40 + i] = (s > 0.f) ? (s + 1.f) : __expf(s);
        }
        #pragma unroll
        for (int i=0; i<40; i++)
            dout[OFF_MU + m*40 + i] = v[50+i] + gSm[SM_BMU+i];
    }
}

// ---------------------------------------------------------------------------
// blocks 0..255: outs = fp32 copy of tgt; blocks 256..383: mask
__global__ __launch_bounds__(256) void k_misc(const float* __restrict__ tgt,
    const int* __restrict__ dur, float* __restrict__ dout)
{
    if (blockIdx.x < 256){
        int i = blockIdx.x*256 + threadIdx.x;
        ((float4*)dout)[i] = ((const float4*)tgt)[i];
    } else {
        __shared__ int red[256];
        int b = blockIdx.x - 256;
        int c = 0;
        for (int s = threadIdx.x; s < S_; s += 256) c += (dur[b*S_ + s] > 0) ? 1 : 0;
        red[threadIdx.x] = c;
        __syncthreads();
        for (int off=128; off>0; off>>=1){
            if (threadIdx.x < off) red[threadIdx.x] += red[threadIdx.x+off];
            __syncthreads();
        }
        int snt = red[0];
        for (int s = threadIdx.x; s < S_; s += 256)
            dout[OFF_MASK + (size_t)b*S_ + s] = (s >= snt) ? 1.f : 0.f;
    }
}

// ---------------------------------------------------------------------------
extern "C" void kernel_launch(void* const* d_in, const int* in_sizes, int n_in,
                              void* d_out, int out_size, void* d_ws, size_t ws_size,
                              hipStream_t stream)
{
    (void)d_ws; (void)ws_size;
    const float* enc  = (const float*)d_in[0];
    const float* tgt  = (const float*)d_in[1];
    const int*   dur  = (const int*)  d_in[2];
    const float* Wpre = (const float*)d_in[3];
    const float* bpre = (const float*)d_in[4];
    const float* Wih0 = (const float*)d_in[5];
    const float* Whh0 = (const float*)d_in[6];
    const float* bih0 = (const float*)d_in[7];
    const float* bhh0 = (const float*)d_in[8];
    const float* Wih1 = (const float*)d_in[9];
    const float* Whh1 = (const float*)d_in[10];
    const float* bih1 = (const float*)d_in[11];
    const float* bhh1 = (const float*)d_in[12];
    const float* Wpi  = (const float*)d_in[13];
    const float* bpi  = (const float*)d_in[14];
    const float* Wsig = (const float*)d_in[15];
    const float* bsig = (const float*)d_in[16];
    const float* Wmu  = (const float*)d_in[17];
    const float* bmu  = (const float*)d_in[18];
    float* dout = (float*)d_out;

    hipLaunchKernelGGL(k_ingest, dim3(4313), dim3(256), 0, stream,
                       Wih0, Whh0, Wih1, Whh1, Wpi, Wsig, Wmu,
                       Wpre, bpre, bih0, bhh0, bih1, bhh1, bpi, bsig, bmu, tgt);
    hipLaunchKernelGGL(k_gi0,  dim3(1024), dim3(256), 0, stream, enc);
    hipLaunchKernelGGL(k_rec,  dim3(32),   dim3(256), 0, stream, 0);
    hipLaunchKernelGGL(k_gi1,  dim3(1024), dim3(256), 0, stream);
    hipLaunchKernelGGL(k_rec,  dim3(32),   dim3(256), 0, stream, 1);
    hipLaunchKernelGGL(k_proj, dim3(512),  dim3(256), 0, stream, enc, dout);
    hipLaunchKernelGGL(k_misc, dim3(384),  dim3(256), 0, stream, tgt, dur, dout);
}

// Round 7
// 1858.723 us; speedup vs baseline: 1.4557x; 1.0661x over previous
//
#include <hip/hip_runtime.h>
#include <hip/hip_bf16.h>
#include <stdint.h>

#define B_   128
#define S_   512
#define C_   256
#define DG_  256

// d_out offsets (fp32 elements): outs, pi, sigma, mu, mask
#define OFF_PI   262144
#define OFF_SIG  917504
#define OFF_MU   3538944
#define OFF_MASK 6160384

typedef __hip_bfloat16 bf16;
typedef __bf16 bf16x8 __attribute__((ext_vector_type(8)));
typedef float  f32x4  __attribute__((ext_vector_type(4)));
typedef unsigned int u32;
typedef unsigned int u32x4 __attribute__((ext_vector_type(4)));

// ---- staging in device globals (zero d_ws dependence) ----
__device__ __align__(16) bf16  gWmain[768*256];   // Wih0[:, :256]
__device__ __align__(16) bf16  gWHH0 [768*256];
__device__ __align__(16) bf16  gWIH1 [768*256];
__device__ __align__(16) bf16  gWHH1 [768*256];
__device__ __align__(16) bf16  gWcat [96*512];    // [W_pi; W_sigma; W_mu; 0]
__device__ __align__(16) float gWtail[768*4];     // Wih0[:, 256:260] fp32
__device__ __align__(16) float gSm   [3200];      // small params fp32
__device__ __align__(16) bf16  gHbuf [B_*S_*DG_]; // h1 per (b,t), b-major (32 MB)
__device__ __align__(16) bf16  gH0   [B_*S_*DG_]; // h0 per (t,b), t-major (32 MB)
__device__ __align__(16) float gGi0  [50331648];  // gi0[t][b][768] fp32 (201 MB)
__device__ __align__(16) float gGi1  [50331648];  // gi1[t][b][768] fp32 (201 MB)
__device__ __align__(16) float gPn   [65536*4];   // prenet per (b,t)

// gSm offsets
#define SM_WPRE 0
#define SM_BPRE 16
#define SM_BIH0 20
#define SM_BHH0 788
#define SM_BIH1 1556
#define SM_BHH1 2324
#define SM_BPI  3092
#define SM_BSIG 3102
#define SM_BMU  3142

__device__ __forceinline__ bf16  f2b(float x){ return __float2bfloat16(x); }
__device__ __forceinline__ unsigned short b2u(bf16 x){
    union { bf16 b; unsigned short u; } c; c.b = x; return c.u;
}
__device__ __forceinline__ float sigm(float x){ return 1.f/(1.f + __expf(-x)); }
__device__ __forceinline__ float rcp_fast(float x){
    float r; asm("v_rcp_f32 %0, %1" : "=v"(r) : "v"(x)); return r;
}
__device__ __forceinline__ u32 cvtpk_bf16(float lo, float hi){
    u32 r; asm("v_cvt_pk_bf16_f32 %0, %1, %2" : "=v"(r) : "v"(lo), "v"(hi)); return r;
}
__device__ __forceinline__ f32x4 mfma16(bf16x8 a, bf16x8 b, f32x4 c){
    return __builtin_amdgcn_mfma_f32_16x16x32_bf16(a, b, c, 0, 0, 0);
}
__device__ __forceinline__ bf16x8 u2b(u32x4 x){
    union { u32x4 u; bf16x8 b; } c; c.u = x; return c.b;
}
__device__ __forceinline__ bf16x8 cvt8(const float* f){
    float4 a = *reinterpret_cast<const float4*>(f);
    float4 c = *reinterpret_cast<const float4*>(f + 4);
    bf16 o[8] = { f2b(a.x),f2b(a.y),f2b(a.z),f2b(a.w),
                  f2b(c.x),f2b(c.y),f2b(c.z),f2b(c.w) };
    return *reinterpret_cast<bf16x8*>(o);
}

// ---------------------------------------------------------------------------
// ingest: canonicalize fp32 params into device globals + prenet
#define IN_N0 199680
#define IN_N1 396288
#define IN_N2 592896
#define IN_N3 789504
#define IN_N4 838656
#define IN_N5 841838
#define IN_N6 1103982
__global__ __launch_bounds__(256) void k_ingest(
    const float* __restrict__ Wih0, const float* __restrict__ Whh0,
    const float* __restrict__ Wih1, const float* __restrict__ Whh1,
    const float* __restrict__ Wpi, const float* __restrict__ Wsig,
    const float* __restrict__ Wmu,
    const float* __restrict__ Wpre, const float* __restrict__ bpre,
    const float* __restrict__ bih0, const float* __restrict__ bhh0,
    const float* __restrict__ bih1, const float* __restrict__ bhh1,
    const float* __restrict__ bpi, const float* __restrict__ bsig,
    const float* __restrict__ bmu, const float* __restrict__ tgt)
{
    int j = blockIdx.x*256 + threadIdx.x;
    if (j < IN_N0){
        int r = j/260, c = j - r*260;
        float v = Wih0[j];
        if (c < 256) gWmain[r*256 + c] = f2b(v);
        else         gWtail[r*4 + (c-256)] = v;
    } else if (j < IN_N1){
        int k = j - IN_N0; gWHH0[k] = f2b(Whh0[k]);
    } else if (j < IN_N2){
        int k = j - IN_N1; gWIH1[k] = f2b(Wih1[k]);
    } else if (j < IN_N3){
        int k = j - IN_N2; gWHH1[k] = f2b(Whh1[k]);
    } else if (j < IN_N4){
        int k = j - IN_N3; int r = k >> 9, c = k & 511;
        float v = 0.f;
        if      (r < 10) v = Wpi[r*512 + c];
        else if (r < 50) v = Wsig[(r-10)*512 + c];
        else if (r < 90) v = Wmu[(r-50)*512 + c];
        gWcat[k] = f2b(v);
    } else if (j < IN_N5){
        int k = j - IN_N4;
        float v;
        if      (k < 16)   v = Wpre[k];
        else if (k < 20)   v = bpre[k-16];
        else if (k < 788)  v = bih0[k-20];
        else if (k < 1556) v = bhh0[k-788];
        else if (k < 2324) v = bih1[k-1556];
        else if (k < 3092) v = bhh1[k-2324];
        else if (k < 3102) v = bpi[k-3092];
        else if (k < 3142) v = bsig[k-3102];
        else               v = bmu[k-3142];
        gSm[k] = v;
    } else if (j < IN_N6){
        // prenet: pn[m][jj] = bpre[jj] + sum_q Wpre[jj][q]*tgt[m-1][q]  (m = b*512+t)
        int k = j - IN_N5, m = k>>2, jj = k&3, tq = m&511;
        float acc = bpre[jj];
        if (tq){
            const float* pv = tgt + (size_t)(m-1)*4;
            #pragma unroll
            for (int q=0;q<4;q++) acc += Wpre[jj*4+q]*pv[q];
        }
        gPn[m*4+jj] = acc;
    }
}

// ---------------------------------------------------------------------------
// k_gi0: gi0[t][b][n] = (Wih0 @ [enc;prenet])[n] + bih0[n] (+ bhh0[n] folded
// for the r/z gate halves, n<512 — pure-additive, so order-only fp change).
__global__ __launch_bounds__(256) void k_gi0(const float* __restrict__ enc)
{
    const int tid = threadIdx.x, w = tid>>6, lane = tid&63;
    const int col = lane&15, quad = lane>>4;
    const int m0 = blockIdx.x*64 + w*16;

    bf16x8 aF[8];
    #pragma unroll
    for (int kt=0; kt<8; kt++)
        aF[kt] = cvt8(enc + (size_t)(m0+col)*256 + kt*32 + quad*8);

    float4 pnr[4];
    #pragma unroll
    for (int r=0; r<4; r++)
        pnr[r] = *reinterpret_cast<const float4*>(gPn + (size_t)(m0 + quad*4 + r)*4);
    const int mrow = m0 + quad*4;

    for (int nt=0; nt<48; nt++){
        const int n = nt*16 + col;
        f32x4 acc = {0.f,0.f,0.f,0.f};
        #pragma unroll
        for (int kt=0; kt<8; kt++){
            bf16x8 bW = *reinterpret_cast<const bf16x8*>(gWmain + (size_t)n*256 + kt*32 + quad*8);
            acc = mfma16(aF[kt], bW, acc);
        }
        float4 wt = ((const float4*)gWtail)[n];
        float  bi = gSm[SM_BIH0 + n] + ((n < 512) ? gSm[SM_BHH0 + n] : 0.f);
        #pragma unroll
        for (int r=0; r<4; r++){
            int m = mrow + r; int bq = m>>9, tq = m&511;
            float v = acc[r] + bi + wt.x*pnr[r].x + wt.y*pnr[r].y
                              + wt.z*pnr[r].z + wt.w*pnr[r].w;
            gGi0[((size_t)tq*128 + bq)*768 + n] = v;
        }
    }
}

// ---------------------------------------------------------------------------
// k_gi1: gi1[t][b][n] = (Wih1 @ h0[t][b])[n] + bih1[n] (+ bhh1[n] for n<512).
__global__ __launch_bounds__(256) void k_gi1()
{
    const int tid = threadIdx.x, w = tid>>6, lane = tid&63;
    const int col = lane&15, quad = lane>>4;
    const int m0 = blockIdx.x*64 + w*16;

    bf16x8 aF[8];
    #pragma unroll
    for (int kt=0; kt<8; kt++)
        aF[kt] = *reinterpret_cast<const bf16x8*>(gH0 + (size_t)(m0+col)*256 + kt*32 + quad*8);

    for (int nt=0; nt<48; nt++){
        const int n = nt*16 + col;
        f32x4 acc = {0.f,0.f,0.f,0.f};
        #pragma unroll
        for (int kt=0; kt<8; kt++){
            bf16x8 bW = *reinterpret_cast<const bf16x8*>(gWIH1 + (size_t)n*256 + kt*32 + quad*8);
            acc = mfma16(aF[kt], bW, acc);
        }
        float bi = gSm[SM_BIH1 + n] + ((n < 512) ? gSm[SM_BHH1 + n] : 0.f);
        #pragma unroll
        for (int r=0; r<4; r++)
            gGi1[((size_t)(m0 + quad*4 + r))*768 + n] = acc[r] + bi;
    }
}

// ---------------------------------------------------------------------------
// k_rec: sequential ZoneOut-GRU layer. 32 blocks x 512 thr = 8 waves,
// 2 waves/SIMD (R6 was 1 wave/SIMD: single-wave MFMA issue ~16cyc/instr,
// MfmaUtil-derived -> the whole step serialized on one wave. 2 waves/SIMD
// interleave MFMA/VALU/ds phases). Block = 4 batches. Wave w owns
// q = {2w, 2w+1} -> 6 tiles: 5 AGPR-resident (asm mfma "a", 160 regs),
// 1 in LDS (64 KB, contiguous per-lane = conflict-free). 256 unified
// regs/lane (registers forbid a 2nd block/CU -> residency stable).
// Lane gate-processes 2 rows: c4=col&3 (batch), qi=(col>>2)&1, sub=col>>3,
// dims d = (2w+qi)*16 + quad*4 + sub*2 + {0,1}. One raw s_barrier/step,
// lgkmcnt-only (h double-buffered; gi loads/stores float across barrier).
__global__ __launch_bounds__(512, 2) void k_rec(int layer)
{
    __shared__ bf16 sW[8][8][64][8];   // 64 KB: per-wave LDS tile (g=2, q=2w+1)
    __shared__ bf16 hv[2][4][272];     // double-buffered h, 4 batches

    const bf16*  __restrict__ W  = layer ? gWHH1 : gWHH0;
    const float* __restrict__ gi = layer ? gGi1  : gGi0;
    const int smOff = layer ? SM_BHH1 : SM_BHH0;
    bf16* __restrict__ hout = layer ? gHbuf : gH0;

    const int tid = threadIdx.x, w = tid>>6, lane = tid&63;
    const int col = lane&15, quad = lane>>4;
    const int bg4 = blockIdx.x*4;

    for (int i=tid; i<2*4*272; i+=512) (&hv[0][0][0])[i] = f2b(0.f);

    // ---- 5 AGPR tiles: j -> (g,qi) = (0,0),(1,0),(2,0),(0,1),(1,1) ----
    u32x4 wA[5][8];
    #pragma unroll
    for (int j=0;j<5;j++){
        const int g  = (j<3) ? j : (j-3);
        const int qi = (j<3) ? 0 : 1;
        const bf16* Wr = W + ((size_t)(g*256 + (2*w+qi)*16 + col))*256;
        #pragma unroll
        for (int kt=0;kt<8;kt++){
            wA[j][kt] = *reinterpret_cast<const u32x4*>(Wr + kt*32 + quad*8);
            asm volatile("" : "+a"(wA[j][kt]));   // park in AGPR, no remat
        }
    }
    // ---- LDS tile (g=2, q=2w+1) ----
    {
        const bf16* Wr = W + ((size_t)(2*256 + (2*w+1)*16 + col))*256;
        #pragma unroll
        for (int kt=0;kt<8;kt++)
            *reinterpret_cast<bf16x8*>(&sW[w][kt][lane][0]) =
                *reinterpret_cast<const bf16x8*>(Wr + kt*32 + quad*8);
    }

    // ---- per-lane gate geometry: 2 rows ----
    const int c4 = col&3, qi = (col>>2)&1, sub = col>>3;
    const int q = 2*w + qi;
    const int d = q*16 + quad*4 + sub*2;
    float2 bhn = *reinterpret_cast<const float2*>(&gSm[smOff + 512 + d]);
    const float* gib = gi + (size_t)(bg4 + c4)*768 + d;
    bf16* hop; size_t hstep;
    if (layer){ hop = hout + ((size_t)(bg4+c4)*512)*256 + d; hstep = 256; }      // b-major
    else      { hop = hout + (size_t)(bg4+c4)*256 + d;       hstep = 128*256; }  // t-major
    float h0 = 0.f, h1 = 0.f;

    // ---- prologue: gi(0) ----
    float2 gr = *reinterpret_cast<const float2*>(gib);
    float2 gz = *reinterpret_cast<const float2*>(gib + 256);
    float2 gn = *reinterpret_cast<const float2*>(gib + 512);

    __syncthreads();

    #pragma unroll 1
    for (int t=0; t<S_; t++){
        // ---- issue gi(t+1) loads FIRST; fence pins them at loop top ----
        float2 pr, pz, pn2;
        if (t+1 < S_){
            const float* gq = gib + (size_t)(t+1)*98304;   // 128*768
            pr  = *reinterpret_cast<const float2*>(gq);
            pz  = *reinterpret_cast<const float2*>(gq + 256);
            pn2 = *reinterpret_cast<const float2*>(gq + 512);
        }
        __builtin_amdgcn_sched_barrier(0);

        f32x4 acc[6];
        #pragma unroll
        for (int j=0;j<6;j++) acc[j] = f32x4{0.f,0.f,0.f,0.f};
        asm volatile("s_nop 2" :::);   // VALU-write -> MFMA-read hazard guard

        const bf16* hrow = &hv[t&1][c4][0];
        #pragma unroll
        for (int kt=0;kt<8;kt++){
            u32x4 hbu = *reinterpret_cast<const u32x4*>(hrow + kt*32 + quad*8);
            #pragma unroll
            for (int j=0;j<5;j++)
                asm volatile("v_mfma_f32_16x16x32_bf16 %0, %1, %2, %0"
                             : "+v"(acc[j]) : "a"(wA[j][kt]), "v"(hbu));
            bf16x8 s5 = *reinterpret_cast<const bf16x8*>(&sW[w][kt][lane][0]);
            acc[5] = mfma16(s5, u2b(hbu), acc[5]);
        }
        asm volatile("s_nop 7\n\ts_nop 7" :::);   // MFMA-write -> VALU-read guard

        // ---- select this lane's accumulators: qi picks q-tile, sub picks rows ----
        f32x4 aR = qi ? acc[3] : acc[0];
        f32x4 aZ = qi ? acc[4] : acc[1];
        f32x4 aN = qi ? acc[5] : acc[2];
        float ar0 = sub ? aR[2] : aR[0], ar1 = sub ? aR[3] : aR[1];
        float az0 = sub ? aZ[2] : aZ[0], az1 = sub ? aZ[3] : aZ[1];
        float an0 = sub ? aN[2] : aN[0], an1 = sub ? aN[3] : aN[1];

        // ---- gates (same formula; rcp-approx divisions) ----
        float rr0 = rcp_fast(1.f + __expf(-(gr.x + ar0)));
        float zz0 = rcp_fast(1.f + __expf(-(gz.x + az0)));
        float xn0 = gn.x + rr0*(an0 + bhn.x);
        float nn0 = 1.f - 2.f*rcp_fast(__expf(2.f*xn0) + 1.f);
        float v0  = 0.1f*h0 + 0.9f*((1.f-zz0)*nn0 + zz0*h0);
        h0 = v0;
        float rr1 = rcp_fast(1.f + __expf(-(gr.y + ar1)));
        float zz1 = rcp_fast(1.f + __expf(-(gz.y + az1)));
        float xn1 = gn.y + rr1*(an1 + bhn.y);
        float nn1 = 1.f - 2.f*rcp_fast(__expf(2.f*xn1) + 1.f);
        float v1  = 0.1f*h1 + 0.9f*((1.f-zz1)*nn1 + zz1*h1);
        h1 = v1;

        // ---- pack bf16 (RNE), write LDS + global H ----
        u32 u = cvtpk_bf16(v0, v1);
        *reinterpret_cast<u32*>(&hv[(t&1)^1][c4][d]) = u;
        *reinterpret_cast<u32*>(hop) = u;  hop += hstep;

        gr = pr; gz = pz; gn = pn2;

        // ---- one barrier/step: LDS visible, NO vmcnt drain ----
        asm volatile("s_waitcnt lgkmcnt(0)" ::: "memory");
        __builtin_amdgcn_sched_barrier(0);
        __builtin_amdgcn_s_barrier();
        __builtin_amdgcn_sched_barrier(0);
    }
}

// ---------------------------------------------------------------------------
// Fused projection + heads: 512 blocks x 128 rows. [H|enc]@Wcat^T -> LDS ->
// softmax/elu/mu, fp32 stores.
__global__ __launch_bounds__(256) void k_proj(
    const float* __restrict__ enc, float* __restrict__ dout)
{
    __shared__ float st[128][100];
    const int tid = threadIdx.x, w = tid>>6, lane = tid&63;
    const int col = lane&15, quad = lane>>4;
    const int Mb = blockIdx.x*128;
    const int M0 = Mb + w*32;

    f32x4 acc[2][6];
    #pragma unroll
    for (int mt=0; mt<2; mt++)
        #pragma unroll
        for (int nt=0; nt<6; nt++) acc[mt][nt] = f32x4{0.f,0.f,0.f,0.f};

    #pragma unroll
    for (int kt=0; kt<16; kt++){
        bf16x8 a0, a1;
        if (kt < 8){
            a0 = *reinterpret_cast<const bf16x8*>(gHbuf + (size_t)(M0 +      col)*DG_ + kt*32 + quad*8);
            a1 = *reinterpret_cast<const bf16x8*>(gHbuf + (size_t)(M0 + 16 + col)*DG_ + kt*32 + quad*8);
        } else {
            a0 = cvt8(enc + (size_t)(M0 +      col)*C_ + (kt-8)*32 + quad*8);
            a1 = cvt8(enc + (size_t)(M0 + 16 + col)*C_ + (kt-8)*32 + quad*8);
        }
        #pragma unroll
        for (int nt=0; nt<6; nt++){
            bf16x8 b = *reinterpret_cast<const bf16x8*>(gWcat + (size_t)(nt*16 + col)*512 + kt*32 + quad*8);
            acc[0][nt] = mfma16(a0, b, acc[0][nt]);
            acc[1][nt] = mfma16(a1, b, acc[1][nt]);
        }
    }
    #pragma unroll
    for (int nt=0; nt<6; nt++)
        #pragma unroll
        for (int mt=0; mt<2; mt++)
            #pragma unroll
            for (int r=0; r<4; r++)
                st[w*32 + mt*16 + quad*4 + r][nt*16 + col] = acc[mt][nt][r];
    __syncthreads();

    if (tid < 128){
        const float* v = st[tid];
        const size_t m = (size_t)Mb + tid;
        float x[10], mx = -1e30f;
        #pragma unroll
        for (int g=0; g<10; g++){ x[g] = v[g] + gSm[SM_BPI+g]; mx = fmaxf(mx, x[g]); }
        float sum = 0.f;
        #pragma unroll
        for (int g=0; g<10; g++){ x[g] = __expf(x[g]-mx); sum += x[g]; }
        float inv = 1.f/sum;
        #pragma unroll
        for (int g=0; g<10; g++)
            dout[OFF_PI + m*10 + g] = x[g]*inv;
        #pragma unroll
        for (int i=0; i<40; i++){
            float s = v[10+i] + gSm[SM_BSIG+i];
            dout[OFF_SIG + m*40 + i] = (s > 0.f) ? (s + 1.f) : __expf(s);
        }
        #pragma unroll
        for (int i=0; i<40; i++)
            dout[OFF_MU + m*40 + i] = v[50+i] + gSm[SM_BMU+i];
    }
}

// ---------------------------------------------------------------------------
// blocks 0..255: outs = fp32 copy of tgt; blocks 256..383: mask
__global__ __launch_bounds__(256) void k_misc(const float* __restrict__ tgt,
    const int* __restrict__ dur, float* __restrict__ dout)
{
    if (blockIdx.x < 256){
        int i = blockIdx.x*256 + threadIdx.x;
        ((float4*)dout)[i] = ((const float4*)tgt)[i];
    } else {
        __shared__ int red[256];
        int b = blockIdx.x - 256;
        int c = 0;
        for (int s = threadIdx.x; s < S_; s += 256) c += (dur[b*S_ + s] > 0) ? 1 : 0;
        red[threadIdx.x] = c;
        __syncthreads();
        for (int off=128; off>0; off>>=1){
            if (threadIdx.x < off) red[threadIdx.x] += red[threadIdx.x+off];
            __syncthreads();
        }
        int snt = red[0];
        for (int s = threadIdx.x; s < S_; s += 256)
            dout[OFF_MASK + (size_t)b*S_ + s] = (s >= snt) ? 1.f : 0.f;
    }
}

// ---------------------------------------------------------------------------
extern "C" void kernel_launch(void* const* d_in, const int* in_sizes, int n_in,
                              void* d_out, int out_size, void* d_ws, size_t ws_size,
                              hipStream_t stream)
{
    (void)d_ws; (void)ws_size;
    const float* enc  = (const float*)d_in[0];
    const float* tgt  = (const float*)d_in[1];
    const int*   dur  = (const int*)  d_in[2];
    const float* Wpre = (const float*)d_in[3];
    const float* bpre = (const float*)d_in[4];
    const float* Wih0 = (const float*)d_in[5];
    const float* Whh0 = (const float*)d_in[6];
    const float* bih0 = (const float*)d_in[7];
    const float* bhh0 = (const float*)d_in[8];
    const float* Wih1 = (const float*)d_in[9];
    const float* Whh1 = (const float*)d_in[10];
    const float* bih1 = (const float*)d_in[11];
    const float* bhh1 = (const float*)d_in[12];
    const float* Wpi  = (const float*)d_in[13];
    const float* bpi  = (const float*)d_in[14];
    const float* Wsig = (const float*)d_in[15];
    const float* bsig = (const float*)d_in[16];
    const float* Wmu  = (const float*)d_in[17];
    const float* bmu  = (const float*)d_in[18];
    float* dout = (float*)d_out;

    hipLaunchKernelGGL(k_ingest, dim3(4313), dim3(256), 0, stream,
                       Wih0, Whh0, Wih1, Whh1, Wpi, Wsig, Wmu,
                       Wpre, bpre, bih0, bhh0, bih1, bhh1, bpi, bsig, bmu, tgt);
    hipLaunchKernelGGL(k_gi0,  dim3(1024), dim3(256), 0, stream, enc);
    hipLaunchKernelGGL(k_rec,  dim3(32),   dim3(512), 0, stream, 0);
    hipLaunchKernelGGL(k_gi1,  dim3(1024), dim3(256), 0, stream);
    hipLaunchKernelGGL(k_rec,  dim3(32),   dim3(512), 0, stream, 1);
    hipLaunchKernelGGL(k_proj, dim3(512),  dim3(256), 0, stream, enc, dout);
    hipLaunchKernelGGL(k_misc, dim3(384),  dim3(256), 0, stream, tgt, dur, dout);
}

// Round 9
// 1789.004 us; speedup vs baseline: 1.5124x; 1.0390x over previous
//
#include <hip/hip_runtime.h>
#include <hip/hip_bf16.h>
#include <stdint.h>

#define B_   128
#define S_   512
#define C_   256
#define DG_  256

// d_out offsets (fp32 elements): outs, pi, sigma, mu, mask
#define OFF_PI   262144
#define OFF_SIG  917504
#define OFF_MU   3538944
#define OFF_MASK 6160384

typedef __hip_bfloat16 bf16;
typedef __bf16 bf16x8 __attribute__((ext_vector_type(8)));
typedef float  f32x4  __attribute__((ext_vector_type(4)));
typedef unsigned int u32;
typedef unsigned int u32x4 __attribute__((ext_vector_type(4)));

// ---- staging in device globals (zero d_ws dependence) ----
__device__ __align__(16) bf16  gWmain[768*256];   // Wih0[:, :256]
__device__ __align__(16) bf16  gWHH0 [768*256];
__device__ __align__(16) bf16  gWIH1 [768*256];
__device__ __align__(16) bf16  gWHH1 [768*256];
__device__ __align__(16) bf16  gWcat [96*512];    // [W_pi; W_sigma; W_mu; 0]
__device__ __align__(16) float gWtail[768*4];     // Wih0[:, 256:260] fp32
__device__ __align__(16) float gSm   [3200];      // small params fp32
__device__ __align__(16) bf16  gHbuf [B_*S_*DG_]; // h1 per (b,t), b-major (32 MB)
__device__ __align__(16) bf16  gH0   [B_*S_*DG_]; // h0 per (t,b), t-major (32 MB)
__device__ __align__(16) float gGi0  [50331648];  // gi0[t][b][768] fp32 (201 MB)
__device__ __align__(16) float gGi1  [50331648];  // gi1[t][b][768] fp32 (201 MB)
__device__ __align__(16) float gPn   [65536*4];   // prenet per (b,t)

// gSm offsets
#define SM_WPRE 0
#define SM_BPRE 16
#define SM_BIH0 20
#define SM_BHH0 788
#define SM_BIH1 1556
#define SM_BHH1 2324
#define SM_BPI  3092
#define SM_BSIG 3102
#define SM_BMU  3142

__device__ __forceinline__ bf16  f2b(float x){ return __float2bfloat16(x); }
__device__ __forceinline__ unsigned short b2u(bf16 x){
    union { bf16 b; unsigned short u; } c; c.b = x; return c.u;
}
__device__ __forceinline__ float sigm(float x){ return 1.f/(1.f + __expf(-x)); }
__device__ __forceinline__ float rcp_fast(float x){
    float r; asm("v_rcp_f32 %0, %1" : "=v"(r) : "v"(x)); return r;
}
__device__ __forceinline__ u32 cvtpk_bf16(float lo, float hi){
    u32 r; asm("v_cvt_pk_bf16_f32 %0, %1, %2" : "=v"(r) : "v"(lo), "v"(hi)); return r;
}
__device__ __forceinline__ f32x4 mfma16(bf16x8 a, bf16x8 b, f32x4 c){
    return __builtin_amdgcn_mfma_f32_16x16x32_bf16(a, b, c, 0, 0, 0);
}
__device__ __forceinline__ bf16x8 u2b(u32x4 x){
    union { u32x4 u; bf16x8 b; } c; c.u = x; return c.b;
}
__device__ __forceinline__ bf16x8 cvt8(const float* f){
    float4 a = *reinterpret_cast<const float4*>(f);
    float4 c = *reinterpret_cast<const float4*>(f + 4);
    bf16 o[8] = { f2b(a.x),f2b(a.y),f2b(a.z),f2b(a.w),
                  f2b(c.x),f2b(c.y),f2b(c.z),f2b(c.w) };
    return *reinterpret_cast<bf16x8*>(o);
}

// ---------------------------------------------------------------------------
// ingest: canonicalize fp32 params into device globals + prenet
#define IN_N0 199680
#define IN_N1 396288
#define IN_N2 592896
#define IN_N3 789504
#define IN_N4 838656
#define IN_N5 841838
#define IN_N6 1103982
__global__ __launch_bounds__(256) void k_ingest(
    const float* __restrict__ Wih0, const float* __restrict__ Whh0,
    const float* __restrict__ Wih1, const float* __restrict__ Whh1,
    const float* __restrict__ Wpi, const float* __restrict__ Wsig,
    const float* __restrict__ Wmu,
    const float* __restrict__ Wpre, const float* __restrict__ bpre,
    const float* __restrict__ bih0, const float* __restrict__ bhh0,
    const float* __restrict__ bih1, const float* __restrict__ bhh1,
    const float* __restrict__ bpi, const float* __restrict__ bsig,
    const float* __restrict__ bmu, const float* __restrict__ tgt)
{
    int j = blockIdx.x*256 + threadIdx.x;
    if (j < IN_N0){
        int r = j/260, c = j - r*260;
        float v = Wih0[j];
        if (c < 256) gWmain[r*256 + c] = f2b(v);
        else         gWtail[r*4 + (c-256)] = v;
    } else if (j < IN_N1){
        int k = j - IN_N0; gWHH0[k] = f2b(Whh0[k]);
    } else if (j < IN_N2){
        int k = j - IN_N1; gWIH1[k] = f2b(Wih1[k]);
    } else if (j < IN_N3){
        int k = j - IN_N2; gWHH1[k] = f2b(Whh1[k]);
    } else if (j < IN_N4){
        int k = j - IN_N3; int r = k >> 9, c = k & 511;
        float v = 0.f;
        if      (r < 10) v = Wpi[r*512 + c];
        else if (r < 50) v = Wsig[(r-10)*512 + c];
        else if (r < 90) v = Wmu[(r-50)*512 + c];
        gWcat[k] = f2b(v);
    } else if (j < IN_N5){
        int k = j - IN_N4;
        float v;
        if      (k < 16)   v = Wpre[k];
        else if (k < 20)   v = bpre[k-16];
        else if (k < 788)  v = bih0[k-20];
        else if (k < 1556) v = bhh0[k-788];
        else if (k < 2324) v = bih1[k-1556];
        else if (k < 3092) v = bhh1[k-2324];
        else if (k < 3102) v = bpi[k-3092];
        else if (k < 3142) v = bsig[k-3102];
        else               v = bmu[k-3142];
        gSm[k] = v;
    } else if (j < IN_N6){
        // prenet: pn[m][jj] = bpre[jj] + sum_q Wpre[jj][q]*tgt[m-1][q]  (m = b*512+t)
        int k = j - IN_N5, m = k>>2, jj = k&3, tq = m&511;
        float acc = bpre[jj];
        if (tq){
            const float* pv = tgt + (size_t)(m-1)*4;
            #pragma unroll
            for (int q=0;q<4;q++) acc += Wpre[jj*4+q]*pv[q];
        }
        gPn[m*4+jj] = acc;
    }
}

// ---------------------------------------------------------------------------
// k_gi0: gi0[t][b][n] = (Wih0 @ [enc;prenet])[n] + bih0[n] (+ bhh0[n] folded
// for the r/z gate halves, n<512). 256 blocks x 256 thr, block = 256 M-rows:
// wave = 4 row-tiles (rows m0+mt*64), so ONE bW load feeds 4 MFMAs (R7 had
// 1:1 -> every wave streamed the full 384KB weight matrix from L2; 4x less
// weight traffic/CU now, and 1 block/CU means each XCD L2 serves it once).
// kt order & per-row dot products unchanged -> bit-identical gi values.
__global__ __launch_bounds__(256, 1) void k_gi0(const float* __restrict__ enc)
{
    const int tid = threadIdx.x, w = tid>>6, lane = tid&63;
    const int col = lane&15, quad = lane>>4;
    const int m0 = blockIdx.x*256 + w*16;

    bf16x8 aF[4][8];
    #pragma unroll
    for (int mt=0; mt<4; mt++)
        #pragma unroll
        for (int kt=0; kt<8; kt++)
            aF[mt][kt] = cvt8(enc + (size_t)(m0 + mt*64 + col)*256 + kt*32 + quad*8);

    float4 pnr[4][4];
    #pragma unroll
    for (int mt=0; mt<4; mt++)
        #pragma unroll
        for (int r=0; r<4; r++)
            pnr[mt][r] = *reinterpret_cast<const float4*>(gPn + (size_t)(m0 + mt*64 + quad*4 + r)*4);

    for (int nt=0; nt<48; nt++){
        const int n = nt*16 + col;
        f32x4 acc[4];
        #pragma unroll
        for (int mt=0; mt<4; mt++) acc[mt] = f32x4{0.f,0.f,0.f,0.f};
        #pragma unroll
        for (int kt=0; kt<8; kt++){
            bf16x8 bW = *reinterpret_cast<const bf16x8*>(gWmain + (size_t)n*256 + kt*32 + quad*8);
            #pragma unroll
            for (int mt=0; mt<4; mt++)
                acc[mt] = mfma16(aF[mt][kt], bW, acc[mt]);
        }
        float4 wt = ((const float4*)gWtail)[n];
        float  bi = gSm[SM_BIH0 + n] + ((n < 512) ? gSm[SM_BHH0 + n] : 0.f);
        #pragma unroll
        for (int mt=0; mt<4; mt++){
            #pragma unroll
            for (int r=0; r<4; r++){
                int m = m0 + mt*64 + quad*4 + r; int bq = m>>9, tq = m&511;
                float v = acc[mt][r] + bi + wt.x*pnr[mt][r].x + wt.y*pnr[mt][r].y
                                    + wt.z*pnr[mt][r].z + wt.w*pnr[mt][r].w;
                gGi0[((size_t)tq*128 + bq)*768 + n] = v;
            }
        }
    }
}

// ---------------------------------------------------------------------------
// k_gi1: gi1[t][b][n] = (Wih1 @ h0[t][b])[n] + bih1[n] (+ bhh1[n] for n<512).
// Same 256-block / 4-row-tile restructure as k_gi0.
__global__ __launch_bounds__(256, 1) void k_gi1()
{
    const int tid = threadIdx.x, w = tid>>6, lane = tid&63;
    const int col = lane&15, quad = lane>>4;
    const int m0 = blockIdx.x*256 + w*16;

    bf16x8 aF[4][8];
    #pragma unroll
    for (int mt=0; mt<4; mt++)
        #pragma unroll
        for (int kt=0; kt<8; kt++)
            aF[mt][kt] = *reinterpret_cast<const bf16x8*>(gH0 + (size_t)(m0 + mt*64 + col)*256 + kt*32 + quad*8);

    for (int nt=0; nt<48; nt++){
        const int n = nt*16 + col;
        f32x4 acc[4];
        #pragma unroll
        for (int mt=0; mt<4; mt++) acc[mt] = f32x4{0.f,0.f,0.f,0.f};
        #pragma unroll
        for (int kt=0; kt<8; kt++){
            bf16x8 bW = *reinterpret_cast<const bf16x8*>(gWIH1 + (size_t)n*256 + kt*32 + quad*8);
            #pragma unroll
            for (int mt=0; mt<4; mt++)
                acc[mt] = mfma16(aF[mt][kt], bW, acc[mt]);
        }
        float bi = gSm[SM_BIH1 + n] + ((n < 512) ? gSm[SM_BHH1 + n] : 0.f);
        #pragma unroll
        for (int mt=0; mt<4; mt++){
            #pragma unroll
            for (int r=0; r<4; r++)
                gGi1[((size_t)(m0 + mt*64 + quad*4 + r))*768 + n] = acc[mt][r] + bi;
        }
    }
}

// ---------------------------------------------------------------------------
// k_rec: sequential ZoneOut-GRU layer. 32 blocks x 512 thr = 8 waves,
// 2 waves/SIMD. Block = 4 batches. Wave w owns q = {2w, 2w+1} -> 6 tiles:
// 5 AGPR-resident (asm mfma "a", 160 regs), 1 in LDS (64 KB, contiguous
// per-lane = conflict-free). NOTE (R8 lesson): 160 AGPR + ~96 VGPR is the
// 2-waves/SIMD budget ceiling (256/lane); the 6th tile in AGPR forces
// spill-restores adjacent to asm MFMAs whose hazards the compiler does not
// guard for inline asm -> silent corruption. Keep this split FROZEN.
// Lane gate-processes 2 rows: c4=col&3 (batch), qi=(col>>2)&1, sub=col>>3,
// dims d = (2w+qi)*16 + quad*4 + sub*2 + {0,1}. One raw s_barrier/step,
// lgkmcnt-only (h double-buffered; gi loads/stores float across barrier).
__global__ __launch_bounds__(512, 2) void k_rec(int layer)
{
    __shared__ bf16 sW[8][8][64][8];   // 64 KB: per-wave LDS tile (g=2, q=2w+1)
    __shared__ bf16 hv[2][4][272];     // double-buffered h, 4 batches

    const bf16*  __restrict__ W  = layer ? gWHH1 : gWHH0;
    const float* __restrict__ gi = layer ? gGi1  : gGi0;
    const int smOff = layer ? SM_BHH1 : SM_BHH0;
    bf16* __restrict__ hout = layer ? gHbuf : gH0;

    const int tid = threadIdx.x, w = tid>>6, lane = tid&63;
    const int col = lane&15, quad = lane>>4;
    const int bg4 = blockIdx.x*4;

    for (int i=tid; i<2*4*272; i+=512) (&hv[0][0][0])[i] = f2b(0.f);

    // ---- 5 AGPR tiles: j -> (g,qi) = (0,0),(1,0),(2,0),(0,1),(1,1) ----
    u32x4 wA[5][8];
    #pragma unroll
    for (int j=0;j<5;j++){
        const int g  = (j<3) ? j : (j-3);
        const int qi = (j<3) ? 0 : 1;
        const bf16* Wr = W + ((size_t)(g*256 + (2*w+qi)*16 + col))*256;
        #pragma unroll
        for (int kt=0;kt<8;kt++){
            wA[j][kt] = *reinterpret_cast<const u32x4*>(Wr + kt*32 + quad*8);
            asm volatile("" : "+a"(wA[j][kt]));   // park in AGPR, no remat
        }
    }
    // ---- LDS tile (g=2, q=2w+1) ----
    {
        const bf16* Wr = W + ((size_t)(2*256 + (2*w+1)*16 + col))*256;
        #pragma unroll
        for (int kt=0;kt<8;kt++)
            *reinterpret_cast<bf16x8*>(&sW[w][kt][lane][0]) =
                *reinterpret_cast<const bf16x8*>(Wr + kt*32 + quad*8);
    }

    // ---- per-lane gate geometry: 2 rows ----
    const int c4 = col&3, qi = (col>>2)&1, sub = col>>3;
    const int q = 2*w + qi;
    const int d = q*16 + quad*4 + sub*2;
    float2 bhn = *reinterpret_cast<const float2*>(&gSm[smOff + 512 + d]);
    const float* gib = gi + (size_t)(bg4 + c4)*768 + d;
    bf16* hop; size_t hstep;
    if (layer){ hop = hout + ((size_t)(bg4+c4)*512)*256 + d; hstep = 256; }      // b-major
    else      { hop = hout + (size_t)(bg4+c4)*256 + d;       hstep = 128*256; }  // t-major
    float h0 = 0.f, h1 = 0.f;

    // ---- prologue: gi(0) ----
    float2 gr = *reinterpret_cast<const float2*>(gib);
    float2 gz = *reinterpret_cast<const float2*>(gib + 256);
    float2 gn = *reinterpret_cast<const float2*>(gib + 512);

    __syncthreads();

    #pragma unroll 1
    for (int t=0; t<S_; t++){
        // ---- issue gi(t+1) loads FIRST; fence pins them at loop top ----
        float2 pr, pz, pn2;
        if (t+1 < S_){
            const float* gq = gib + (size_t)(t+1)*98304;   // 128*768
            pr  = *reinterpret_cast<const float2*>(gq);
            pz  = *reinterpret_cast<const float2*>(gq + 256);
            pn2 = *reinterpret_cast<const float2*>(gq + 512);
        }
        __builtin_amdgcn_sched_barrier(0);

        f32x4 acc[6];
        #pragma unroll
        for (int j=0;j<6;j++) acc[j] = f32x4{0.f,0.f,0.f,0.f};
        asm volatile("s_nop 2" :::);   // VALU-write -> MFMA-read hazard guard

        const bf16* hrow = &hv[t&1][c4][0];
        #pragma unroll
        for (int kt=0;kt<8;kt++){
            u32x4 hbu = *reinterpret_cast<const u32x4*>(hrow + kt*32 + quad*8);
            #pragma unroll
            for (int j=0;j<5;j++)
                asm volatile("v_mfma_f32_16x16x32_bf16 %0, %1, %2, %0"
                             : "+v"(acc[j]) : "a"(wA[j][kt]), "v"(hbu));
            bf16x8 s5 = *reinterpret_cast<const bf16x8*>(&sW[w][kt][lane][0]);
            acc[5] = mfma16(s5, u2b(hbu), acc[5]);
        }
        asm volatile("s_nop 7\n\ts_nop 7" :::);   // MFMA-write -> VALU-read guard

        // ---- select this lane's accumulators: qi picks q-tile, sub picks rows ----
        f32x4 aR = qi ? acc[3] : acc[0];
        f32x4 aZ = qi ? acc[4] : acc[1];
        f32x4 aN = qi ? acc[5] : acc[2];
        float ar0 = sub ? aR[2] : aR[0], ar1 = sub ? aR[3] : aR[1];
        float az0 = sub ? aZ[2] : aZ[0], az1 = sub ? aZ[3] : aZ[1];
        float an0 = sub ? aN[2] : aN[0], an1 = sub ? aN[3] : aN[1];

        // ---- gates (same formula; rcp-approx divisions) ----
        float rr0 = rcp_fast(1.f + __expf(-(gr.x + ar0)));
        float zz0 = rcp_fast(1.f + __expf(-(gz.x + az0)));
        float xn0 = gn.x + rr0*(an0 + bhn.x);
        float nn0 = 1.f - 2.f*rcp_fast(__expf(2.f*xn0) + 1.f);
        float v0  = 0.1f*h0 + 0.9f*((1.f-zz0)*nn0 + zz0*h0);
        h0 = v0;
        float rr1 = rcp_fast(1.f + __expf(-(gr.y + ar1)));
        float zz1 = rcp_fast(1.f + __expf(-(gz.y + az1)));
        float xn1 = gn.y + rr1*(an1 + bhn.y);
        float nn1 = 1.f - 2.f*rcp_fast(__expf(2.f*xn1) + 1.f);
        float v1  = 0.1f*h1 + 0.9f*((1.f-zz1)*nn1 + zz1*h1);
        h1 = v1;

        // ---- pack bf16 (RNE), write LDS + global H ----
        u32 u = cvtpk_bf16(v0, v1);
        *reinterpret_cast<u32*>(&hv[(t&1)^1][c4][d]) = u;
        *reinterpret_cast<u32*>(hop) = u;  hop += hstep;

        gr = pr; gz = pz; gn = pn2;

        // ---- one barrier/step: LDS visible, NO vmcnt drain ----
        asm volatile("s_waitcnt lgkmcnt(0)" ::: "memory");
        __builtin_amdgcn_sched_barrier(0);
        __builtin_amdgcn_s_barrier();
        __builtin_amdgcn_sched_barrier(0);
    }
}

// ---------------------------------------------------------------------------
// Fused projection + heads: 512 blocks x 128 rows. [H|enc]@Wcat^T -> LDS ->
// softmax/elu/mu, fp32 stores.
__global__ __launch_bounds__(256) void k_proj(
    const float* __restrict__ enc, float* __restrict__ dout)
{
    __shared__ float st[128][100];
    const int tid = threadIdx.x, w = tid>>6, lane = tid&63;
    const int col = lane&15, quad = lane>>4;
    const int Mb = blockIdx.x*128;
    const int M0 = Mb + w*32;

    f32x4 acc[2][6];
    #pragma unroll
    for (int mt=0; mt<2; mt++)
        #pragma unroll
        for (int nt=0; nt<6; nt++) acc[mt][nt] = f32x4{0.f,0.f,0.f,0.f};

    #pragma unroll
    for (int kt=0; kt<16; kt++){
        bf16x8 a0, a1;
        if (kt < 8){
            a0 = *reinterpret_cast<const bf16x8*>(gHbuf + (size_t)(M0 +      col)*DG_ + kt*32 + quad*8);
            a1 = *reinterpret_cast<const bf16x8*>(gHbuf + (size_t)(M0 + 16 + col)*DG_ + kt*32 + quad*8);
        } else {
            a0 = cvt8(enc + (size_t)(M0 +      col)*C_ + (kt-8)*32 + quad*8);
            a1 = cvt8(enc + (size_t)(M0 + 16 + col)*C_ + (kt-8)*32 + quad*8);
        }
        #pragma unroll
        for (int nt=0; nt<6; nt++){
            bf16x8 b = *reinterpret_cast<const bf16x8*>(gWcat + (size_t)(nt*16 + col)*512 + kt*32 + quad*8);
            acc[0][nt] = mfma16(a0, b, acc[0][nt]);
            acc[1][nt] = mfma16(a1, b, acc[1][nt]);
        }
    }
    #pragma unroll
    for (int nt=0; nt<6; nt++)
        #pragma unroll
        for (int mt=0; mt<2; mt++)
            #pragma unroll
            for (int r=0; r<4; r++)
                st[w*32 + mt*16 + quad*4 + r][nt*16 + col] = acc[mt][nt][r];
    __syncthreads();

    if (tid < 128){
        const float* v = st[tid];
        const size_t m = (size_t)Mb + tid;
        float x[10], mx = -1e30f;
        #pragma unroll
        for (int g=0; g<10; g++){ x[g] = v[g] + gSm[SM_BPI+g]; mx = fmaxf(mx, x[g]); }
        float sum = 0.f;
        #pragma unroll
        for (int g=0; g<10; g++){ x[g] = __expf(x[g]-mx); sum += x[g]; }
        float inv = 1.f/sum;
        #pragma unroll
        for (int g=0; g<10; g++)
            dout[OFF_PI + m*10 + g] = x[g]*inv;
        #pragma unroll
        for (int i=0; i<40; i++){
            float s = v[10+i] + gSm[SM_BSIG+i];
            dout[OFF_SIG + m*40 + i] = (s > 0.f) ? (s + 1.f) : __expf(s);
        }
        #pragma unroll
        for (int i=0; i<40; i++)
            dout[OFF_MU + m*40 + i] = v[50+i] + gSm[SM_BMU+i];
    }
}

// ---------------------------------------------------------------------------
// blocks 0..255: outs = fp32 copy of tgt; blocks 256..383: mask
__global__ __launch_bounds__(256) void k_misc(const float* __restrict__ tgt,
    const int* __restrict__ dur, float* __restrict__ dout)
{
    if (blockIdx.x < 256){
        int i = blockIdx.x*256 + threadIdx.x;
        ((float4*)dout)[i] = ((const float4*)tgt)[i];
    } else {
        __shared__ int red[256];
        int b = blockIdx.x - 256;
        int c = 0;
        for (int s = threadIdx.x; s < S_; s += 256) c += (dur[b*S_ + s] > 0) ? 1 : 0;
        red[threadIdx.x] = c;
        __syncthreads();
        for (int off=128; off>0; off>>=1){
            if (threadIdx.x < off) red[threadIdx.x] += red[threadIdx.x+off];
            __syncthreads();
        }
        int snt = red[0];
        for (int s = threadIdx.x; s < S_; s += 256)
            dout[OFF_MASK + (size_t)b*S_ + s] = (s >= snt) ? 1.f : 0.f;
    }
}

// ---------------------------------------------------------------------------
extern "C" void kernel_launch(void* const* d_in, const int* in_sizes, int n_in,
                              void* d_out, int out_size, void* d_ws, size_t ws_size,
                              hipStream_t stream)
{
    (void)d_ws; (void)ws_size;
    const float* enc  = (const float*)d_in[0];
    const float* tgt  = (const float*)d_in[1];
    const int*   dur  = (const int*)  d_in[2];
    const float* Wpre = (const float*)d_in[3];
    const float* bpre = (const float*)d_in[4];
    const float* Wih0 = (const float*)d_in[5];
    const float* Whh0 = (const float*)d_in[6];
    const float* bih0 = (const float*)d_in[7];
    const float* bhh0 = (const float*)d_in[8];
    const float* Wih1 = (const float*)d_in[9];
    const float* Whh1 = (const float*)d_in[10];
    const float* bih1 = (const float*)d_in[11];
    const float* bhh1 = (const float*)d_in[12];
    const float* Wpi  = (const float*)d_in[13];
    const float* bpi  = (const float*)d_in[14];
    const float* Wsig = (const float*)d_in[15];
    const float* bsig = (const float*)d_in[16];
    const float* Wmu  = (const float*)d_in[17];
    const float* bmu  = (const float*)d_in[18];
    float* dout = (float*)d_out;

    hipLaunchKernelGGL(k_ingest, dim3(4313), dim3(256), 0, stream,
                       Wih0, Whh0, Wih1, Whh1, Wpi, Wsig, Wmu,
                       Wpre, bpre, bih0, bhh0, bih1, bhh1, bpi, bsig, bmu, tgt);
    hipLaunchKernelGGL(k_gi0,  dim3(256),  dim3(256), 0, stream, enc);
    hipLaunchKernelGGL(k_rec,  dim3(32),   dim3(512), 0, stream, 0);
    hipLaunchKernelGGL(k_gi1,  dim3(256),  dim3(256), 0, stream);
    hipLaunchKernelGGL(k_rec,  dim3(32),   dim3(512), 0, stream, 1);
    hipLaunchKernelGGL(k_proj, dim3(512),  dim3(256), 0, stream, enc, dout);
    hipLaunchKernelGGL(k_misc, dim3(384),  dim3(256), 0, stream, tgt, dur, dout);
}

// Round 10
// 1788.332 us; speedup vs baseline: 1.5130x; 1.0004x over previous
//
#include <hip/hip_runtime.h>
#include <hip/hip_bf16.h>
#include <stdint.h>

#define B_   128
#define S_   512
#define C_   256
#define DG_  256

// d_out offsets (fp32 elements): outs, pi, sigma, mu, mask
#define OFF_PI   262144
#define OFF_SIG  917504
#define OFF_MU   3538944
#define OFF_MASK 6160384

typedef __hip_bfloat16 bf16;
typedef __bf16 bf16x8 __attribute__((ext_vector_type(8)));
typedef float  f32x4  __attribute__((ext_vector_type(4)));
typedef unsigned int u32;
typedef unsigned int u32x4 __attribute__((ext_vector_type(4)));

// ---- staging in device globals (zero d_ws dependence) ----
__device__ __align__(16) bf16  gWmain[768*256];   // Wih0[:, :256]
__device__ __align__(16) bf16  gWHH0 [768*256];
__device__ __align__(16) bf16  gWIH1 [768*256];
__device__ __align__(16) bf16  gWHH1 [768*256];
__device__ __align__(16) bf16  gWcat [96*512];    // [W_pi; W_sigma; W_mu; 0]
__device__ __align__(16) float gWtail[768*4];     // Wih0[:, 256:260] fp32
__device__ __align__(16) float gSm   [3200];      // small params fp32
__device__ __align__(16) bf16  gHbuf [B_*S_*DG_]; // h1 per (b,t), b-major (32 MB)
__device__ __align__(16) bf16  gH0   [B_*S_*DG_]; // h0 per (t,b), t-major (32 MB)
__device__ __align__(16) float gGi0  [50331648];  // gi0[t][b][768] fp32 (201 MB)
__device__ __align__(16) float gGi1  [50331648];  // gi1[t][b][768] fp32 (201 MB)
__device__ __align__(16) float gPn   [65536*4];   // prenet per (b,t)

// gSm offsets
#define SM_WPRE 0
#define SM_BPRE 16
#define SM_BIH0 20
#define SM_BHH0 788
#define SM_BIH1 1556
#define SM_BHH1 2324
#define SM_BPI  3092
#define SM_BSIG 3102
#define SM_BMU  3142

__device__ __forceinline__ bf16  f2b(float x){ return __float2bfloat16(x); }
__device__ __forceinline__ unsigned short b2u(bf16 x){
    union { bf16 b; unsigned short u; } c; c.b = x; return c.u;
}
__device__ __forceinline__ float sigm(float x){ return 1.f/(1.f + __expf(-x)); }
__device__ __forceinline__ float rcp_fast(float x){
    float r; asm("v_rcp_f32 %0, %1" : "=v"(r) : "v"(x)); return r;
}
__device__ __forceinline__ u32 cvtpk_bf16(float lo, float hi){
    u32 r; asm("v_cvt_pk_bf16_f32 %0, %1, %2" : "=v"(r) : "v"(lo), "v"(hi)); return r;
}
__device__ __forceinline__ f32x4 mfma16(bf16x8 a, bf16x8 b, f32x4 c){
    return __builtin_amdgcn_mfma_f32_16x16x32_bf16(a, b, c, 0, 0, 0);
}
__device__ __forceinline__ bf16x8 u2b(u32x4 x){
    union { u32x4 u; bf16x8 b; } c; c.u = x; return c.b;
}
__device__ __forceinline__ bf16x8 cvt8(const float* f){
    float4 a = *reinterpret_cast<const float4*>(f);
    float4 c = *reinterpret_cast<const float4*>(f + 4);
    bf16 o[8] = { f2b(a.x),f2b(a.y),f2b(a.z),f2b(a.w),
                  f2b(c.x),f2b(c.y),f2b(c.z),f2b(c.w) };
    return *reinterpret_cast<bf16x8*>(o);
}

// ---------------------------------------------------------------------------
// ingest: canonicalize fp32 params into device globals + prenet
#define IN_N0 199680
#define IN_N1 396288
#define IN_N2 592896
#define IN_N3 789504
#define IN_N4 838656
#define IN_N5 841838
#define IN_N6 1103982
__global__ __launch_bounds__(256) void k_ingest(
    const float* __restrict__ Wih0, const float* __restrict__ Whh0,
    const float* __restrict__ Wih1, const float* __restrict__ Whh1,
    const float* __restrict__ Wpi, const float* __restrict__ Wsig,
    const float* __restrict__ Wmu,
    const float* __restrict__ Wpre, const float* __restrict__ bpre,
    const float* __restrict__ bih0, const float* __restrict__ bhh0,
    const float* __restrict__ bih1, const float* __restrict__ bhh1,
    const float* __restrict__ bpi, const float* __restrict__ bsig,
    const float* __restrict__ bmu, const float* __restrict__ tgt)
{
    int j = blockIdx.x*256 + threadIdx.x;
    if (j < IN_N0){
        int r = j/260, c = j - r*260;
        float v = Wih0[j];
        if (c < 256) gWmain[r*256 + c] = f2b(v);
        else         gWtail[r*4 + (c-256)] = v;
    } else if (j < IN_N1){
        int k = j - IN_N0; gWHH0[k] = f2b(Whh0[k]);
    } else if (j < IN_N2){
        int k = j - IN_N1; gWIH1[k] = f2b(Wih1[k]);
    } else if (j < IN_N3){
        int k = j - IN_N2; gWHH1[k] = f2b(Whh1[k]);
    } else if (j < IN_N4){
        int k = j - IN_N3; int r = k >> 9, c = k & 511;
        float v = 0.f;
        if      (r < 10) v = Wpi[r*512 + c];
        else if (r < 50) v = Wsig[(r-10)*512 + c];
        else if (r < 90) v = Wmu[(r-50)*512 + c];
        gWcat[k] = f2b(v);
    } else if (j < IN_N5){
        int k = j - IN_N4;
        float v;
        if      (k < 16)   v = Wpre[k];
        else if (k < 20)   v = bpre[k-16];
        else if (k < 788)  v = bih0[k-20];
        else if (k < 1556) v = bhh0[k-788];
        else if (k < 2324) v = bih1[k-1556];
        else if (k < 3092) v = bhh1[k-2324];
        else if (k < 3102) v = bpi[k-3092];
        else if (k < 3142) v = bsig[k-3102];
        else               v = bmu[k-3142];
        gSm[k] = v;
    } else if (j < IN_N6){
        // prenet: pn[m][jj] = bpre[jj] + sum_q Wpre[jj][q]*tgt[m-1][q]  (m = b*512+t)
        int k = j - IN_N5, m = k>>2, jj = k&3, tq = m&511;
        float acc = bpre[jj];
        if (tq){
            const float* pv = tgt + (size_t)(m-1)*4;
            #pragma unroll
            for (int q=0;q<4;q++) acc += Wpre[jj*4+q]*pv[q];
        }
        gPn[m*4+jj] = acc;
    }
}

// ---------------------------------------------------------------------------
// k_gi0: gi0[t][b][n] = (Wih0 @ [enc;prenet])[n] + bih0[n] (+ bhh0[n] folded
// for the r/z gate halves, n<512). 256 blocks x 256 thr, block = 256 M-rows:
// wave = 4 row-tiles, ONE bW load feeds 4 MFMAs.
__global__ __launch_bounds__(256, 1) void k_gi0(const float* __restrict__ enc)
{
    const int tid = threadIdx.x, w = tid>>6, lane = tid&63;
    const int col = lane&15, quad = lane>>4;
    const int m0 = blockIdx.x*256 + w*16;

    bf16x8 aF[4][8];
    #pragma unroll
    for (int mt=0; mt<4; mt++)
        #pragma unroll
        for (int kt=0; kt<8; kt++)
            aF[mt][kt] = cvt8(enc + (size_t)(m0 + mt*64 + col)*256 + kt*32 + quad*8);

    float4 pnr[4][4];
    #pragma unroll
    for (int mt=0; mt<4; mt++)
        #pragma unroll
        for (int r=0; r<4; r++)
            pnr[mt][r] = *reinterpret_cast<const float4*>(gPn + (size_t)(m0 + mt*64 + quad*4 + r)*4);

    for (int nt=0; nt<48; nt++){
        const int n = nt*16 + col;
        f32x4 acc[4];
        #pragma unroll
        for (int mt=0; mt<4; mt++) acc[mt] = f32x4{0.f,0.f,0.f,0.f};
        #pragma unroll
        for (int kt=0; kt<8; kt++){
            bf16x8 bW = *reinterpret_cast<const bf16x8*>(gWmain + (size_t)n*256 + kt*32 + quad*8);
            #pragma unroll
            for (int mt=0; mt<4; mt++)
                acc[mt] = mfma16(aF[mt][kt], bW, acc[mt]);
        }
        float4 wt = ((const float4*)gWtail)[n];
        float  bi = gSm[SM_BIH0 + n] + ((n < 512) ? gSm[SM_BHH0 + n] : 0.f);
        #pragma unroll
        for (int mt=0; mt<4; mt++){
            #pragma unroll
            for (int r=0; r<4; r++){
                int m = m0 + mt*64 + quad*4 + r; int bq = m>>9, tq = m&511;
                float v = acc[mt][r] + bi + wt.x*pnr[mt][r].x + wt.y*pnr[mt][r].y
                                    + wt.z*pnr[mt][r].z + wt.w*pnr[mt][r].w;
                gGi0[((size_t)tq*128 + bq)*768 + n] = v;
            }
        }
    }
}

// ---------------------------------------------------------------------------
// k_gi1: gi1[t][b][n] = (Wih1 @ h0[t][b])[n] + bih1[n] (+ bhh1[n] for n<512).
// Same 256-block / 4-row-tile structure as k_gi0.
__global__ __launch_bounds__(256, 1) void k_gi1()
{
    const int tid = threadIdx.x, w = tid>>6, lane = tid&63;
    const int col = lane&15, quad = lane>>4;
    const int m0 = blockIdx.x*256 + w*16;

    bf16x8 aF[4][8];
    #pragma unroll
    for (int mt=0; mt<4; mt++)
        #pragma unroll
        for (int kt=0; kt<8; kt++)
            aF[mt][kt] = *reinterpret_cast<const bf16x8*>(gH0 + (size_t)(m0 + mt*64 + col)*256 + kt*32 + quad*8);

    for (int nt=0; nt<48; nt++){
        const int n = nt*16 + col;
        f32x4 acc[4];
        #pragma unroll
        for (int mt=0; mt<4; mt++) acc[mt] = f32x4{0.f,0.f,0.f,0.f};
        #pragma unroll
        for (int kt=0; kt<8; kt++){
            bf16x8 bW = *reinterpret_cast<const bf16x8*>(gWIH1 + (size_t)n*256 + kt*32 + quad*8);
            #pragma unroll
            for (int mt=0; mt<4; mt++)
                acc[mt] = mfma16(aF[mt][kt], bW, acc[mt]);
        }
        float bi = gSm[SM_BIH1 + n] + ((n < 512) ? gSm[SM_BHH1 + n] : 0.f);
        #pragma unroll
        for (int mt=0; mt<4; mt++){
            #pragma unroll
            for (int r=0; r<4; r++)
                gGi1[((size_t)(m0 + mt*64 + quad*4 + r))*768 + n] = acc[mt][r] + bi;
        }
    }
}

// ---------------------------------------------------------------------------
// k_rec: sequential ZoneOut-GRU layer. 32 blocks x 512 thr = 8 waves,
// 2 waves/SIMD. Block = 4 batches. Wave w owns q = {2w, 2w+1} -> 6 tiles:
// 5 AGPR-resident (asm mfma "a", 160 AGPR) + 1 VGPR-resident ("+v" pin,
// intrinsic mfma -> compiler-managed hazards; R5/R6-proven pattern).
// R9 kept tile 6 in LDS: its 64 ds_read_b128/step/CU were HALF the LDS
// issue-pipe cost (~1540cyc) that bounded the step. At 2 waves/SIMD the
// VGPR and AGPR budgets are separate (~256 each: R7/R9 ran 120V+160A);
// VGPR 120->152 fits. R8 lesson stands: do NOT exceed 160 AGPR (spill
// restores are hazard-unguarded next to asm MFMAs -> silent corruption).
// Per-CU LDS/step is now ONLY 64 hv reads + 8 writes.
// Lane gate-processes 2 rows: c4=col&3 (batch), qi=(col>>2)&1, sub=col>>3,
// dims d = (2w+qi)*16 + quad*4 + sub*2 + {0,1}. One raw s_barrier/step,
// lgkmcnt-only (h double-buffered; gi loads/stores float across barrier).
__global__ __launch_bounds__(512, 2) void k_rec(int layer)
{
    __shared__ bf16 hv[2][4][272];     // double-buffered h, 4 batches

    const bf16*  __restrict__ W  = layer ? gWHH1 : gWHH0;
    const float* __restrict__ gi = layer ? gGi1  : gGi0;
    const int smOff = layer ? SM_BHH1 : SM_BHH0;
    bf16* __restrict__ hout = layer ? gHbuf : gH0;

    const int tid = threadIdx.x, w = tid>>6, lane = tid&63;
    const int col = lane&15, quad = lane>>4;
    const int bg4 = blockIdx.x*4;

    for (int i=tid; i<2*4*272; i+=512) (&hv[0][0][0])[i] = f2b(0.f);

    // ---- 5 AGPR tiles: j -> (g,qi) = (0,0),(1,0),(2,0),(0,1),(1,1) ----
    u32x4 wA[5][8];
    #pragma unroll
    for (int j=0;j<5;j++){
        const int g  = (j<3) ? j : (j-3);
        const int qi = (j<3) ? 0 : 1;
        const bf16* Wr = W + ((size_t)(g*256 + (2*w+qi)*16 + col))*256;
        #pragma unroll
        for (int kt=0;kt<8;kt++){
            wA[j][kt] = *reinterpret_cast<const u32x4*>(Wr + kt*32 + quad*8);
            asm volatile("" : "+a"(wA[j][kt]));   // park in AGPR, no remat
        }
    }
    // ---- 6th tile (g=2, q=2w+1) pinned in VGPRs, consumed by intrinsic ----
    u32x4 wV[8];
    {
        const bf16* Wr = W + ((size_t)(2*256 + (2*w+1)*16 + col))*256;
        #pragma unroll
        for (int kt=0;kt<8;kt++){
            wV[kt] = *reinterpret_cast<const u32x4*>(Wr + kt*32 + quad*8);
            asm volatile("" : "+v"(wV[kt]));      // pin in arch VGPR, no remat
        }
    }

    // ---- per-lane gate geometry: 2 rows ----
    const int c4 = col&3, qi = (col>>2)&1, sub = col>>3;
    const int q = 2*w + qi;
    const int d = q*16 + quad*4 + sub*2;
    float2 bhn = *reinterpret_cast<const float2*>(&gSm[smOff + 512 + d]);
    const float* gib = gi + (size_t)(bg4 + c4)*768 + d;
    bf16* hop; size_t hstep;
    if (layer){ hop = hout + ((size_t)(bg4+c4)*512)*256 + d; hstep = 256; }      // b-major
    else      { hop = hout + (size_t)(bg4+c4)*256 + d;       hstep = 128*256; }  // t-major
    float h0 = 0.f, h1 = 0.f;

    // ---- prologue: gi(0) ----
    float2 gr = *reinterpret_cast<const float2*>(gib);
    float2 gz = *reinterpret_cast<const float2*>(gib + 256);
    float2 gn = *reinterpret_cast<const float2*>(gib + 512);

    __syncthreads();

    #pragma unroll 1
    for (int t=0; t<S_; t++){
        // ---- issue gi(t+1) loads FIRST; fence pins them at loop top ----
        float2 pr, pz, pn2;
        if (t+1 < S_){
            const float* gq = gib + (size_t)(t+1)*98304;   // 128*768
            pr  = *reinterpret_cast<const float2*>(gq);
            pz  = *reinterpret_cast<const float2*>(gq + 256);
            pn2 = *reinterpret_cast<const float2*>(gq + 512);
        }
        __builtin_amdgcn_sched_barrier(0);

        f32x4 acc[6];
        #pragma unroll
        for (int j=0;j<6;j++) acc[j] = f32x4{0.f,0.f,0.f,0.f};
        asm volatile("s_nop 2" :::);   // VALU-write -> MFMA-read hazard guard

        const bf16* hrow = &hv[t&1][c4][0];
        #pragma unroll
        for (int kt=0;kt<8;kt++){
            u32x4 hbu = *reinterpret_cast<const u32x4*>(hrow + kt*32 + quad*8);
            #pragma unroll
            for (int j=0;j<5;j++)
                asm volatile("v_mfma_f32_16x16x32_bf16 %0, %1, %2, %0"
                             : "+v"(acc[j]) : "a"(wA[j][kt]), "v"(hbu));
            acc[5] = mfma16(u2b(wV[kt]), u2b(hbu), acc[5]);
        }
        asm volatile("s_nop 7\n\ts_nop 7" :::);   // MFMA-write -> VALU-read guard

        // ---- select this lane's accumulators: qi picks q-tile, sub picks rows ----
        f32x4 aR = qi ? acc[3] : acc[0];
        f32x4 aZ = qi ? acc[4] : acc[1];
        f32x4 aN = qi ? acc[5] : acc[2];
        float ar0 = sub ? aR[2] : aR[0], ar1 = sub ? aR[3] : aR[1];
        float az0 = sub ? aZ[2] : aZ[0], az1 = sub ? aZ[3] : aZ[1];
        float an0 = sub ? aN[2] : aN[0], an1 = sub ? aN[3] : aN[1];

        // ---- gates (same formula; rcp-approx divisions) ----
        float rr0 = rcp_fast(1.f + __expf(-(gr.x + ar0)));
        float zz0 = rcp_fast(1.f + __expf(-(gz.x + az0)));
        float xn0 = gn.x + rr0*(an0 + bhn.x);
        float nn0 = 1.f - 2.f*rcp_fast(__expf(2.f*xn0) + 1.f);
        float v0  = 0.1f*h0 + 0.9f*((1.f-zz0)*nn0 + zz0*h0);
        h0 = v0;
        float rr1 = rcp_fast(1.f + __expf(-(gr.y + ar1)));
        float zz1 = rcp_fast(1.f + __expf(-(gz.y + az1)));
        float xn1 = gn.y + rr1*(an1 + bhn.y);
        float nn1 = 1.f - 2.f*rcp_fast(__expf(2.f*xn1) + 1.f);
        float v1  = 0.1f*h1 + 0.9f*((1.f-zz1)*nn1 + zz1*h1);
        h1 = v1;

        // ---- pack bf16 (RNE), write LDS + global H ----
        u32 u = cvtpk_bf16(v0, v1);
        *reinterpret_cast<u32*>(&hv[(t&1)^1][c4][d]) = u;
        *reinterpret_cast<u32*>(hop) = u;  hop += hstep;

        gr = pr; gz = pz; gn = pn2;

        // ---- one barrier/step: LDS visible, NO vmcnt drain ----
        asm volatile("s_waitcnt lgkmcnt(0)" ::: "memory");
        __builtin_amdgcn_sched_barrier(0);
        __builtin_amdgcn_s_barrier();
        __builtin_amdgcn_sched_barrier(0);
    }
}

// ---------------------------------------------------------------------------
// Fused projection + heads: 512 blocks x 128 rows. [H|enc]@Wcat^T -> LDS ->
// softmax/elu/mu, fp32 stores.
__global__ __launch_bounds__(256) void k_proj(
    const float* __restrict__ enc, float* __restrict__ dout)
{
    __shared__ float st[128][100];
    const int tid = threadIdx.x, w = tid>>6, lane = tid&63;
    const int col = lane&15, quad = lane>>4;
    const int Mb = blockIdx.x*128;
    const int M0 = Mb + w*32;

    f32x4 acc[2][6];
    #pragma unroll
    for (int mt=0; mt<2; mt++)
        #pragma unroll
        for (int nt=0; nt<6; nt++) acc[mt][nt] = f32x4{0.f,0.f,0.f,0.f};

    #pragma unroll
    for (int kt=0; kt<16; kt++){
        bf16x8 a0, a1;
        if (kt < 8){
            a0 = *reinterpret_cast<const bf16x8*>(gHbuf + (size_t)(M0 +      col)*DG_ + kt*32 + quad*8);
            a1 = *reinterpret_cast<const bf16x8*>(gHbuf + (size_t)(M0 + 16 + col)*DG_ + kt*32 + quad*8);
        } else {
            a0 = cvt8(enc + (size_t)(M0 +      col)*C_ + (kt-8)*32 + quad*8);
            a1 = cvt8(enc + (size_t)(M0 + 16 + col)*C_ + (kt-8)*32 + quad*8);
        }
        #pragma unroll
        for (int nt=0; nt<6; nt++){
            bf16x8 b = *reinterpret_cast<const bf16x8*>(gWcat + (size_t)(nt*16 + col)*512 + kt*32 + quad*8);
            acc[0][nt] = mfma16(a0, b, acc[0][nt]);
            acc[1][nt] = mfma16(a1, b, acc[1][nt]);
        }
    }
    #pragma unroll
    for (int nt=0; nt<6; nt++)
        #pragma unroll
        for (int mt=0; mt<2; mt++)
            #pragma unroll
            for (int r=0; r<4; r++)
                st[w*32 + mt*16 + quad*4 + r][nt*16 + col] = acc[mt][nt][r];
    __syncthreads();

    if (tid < 128){
        const float* v = st[tid];
        const size_t m = (size_t)Mb + tid;
        float x[10], mx = -1e30f;
        #pragma unroll
        for (int g=0; g<10; g++){ x[g] = v[g] + gSm[SM_BPI+g]; mx = fmaxf(mx, x[g]); }
        float sum = 0.f;
        #pragma unroll
        for (int g=0; g<10; g++){ x[g] = __expf(x[g]-mx); sum += x[g]; }
        float inv = 1.f/sum;
        #pragma unroll
        for (int g=0; g<10; g++)
            dout[OFF_PI + m*10 + g] = x[g]*inv;
        #pragma unroll
        for (int i=0; i<40; i++){
            float s = v[10+i] + gSm[SM_BSIG+i];
            dout[OFF_SIG + m*40 + i] = (s > 0.f) ? (s + 1.f) : __expf(s);
        }
        #pragma unroll
        for (int i=0; i<40; i++)
            dout[OFF_MU + m*40 + i] = v[50+i] + gSm[SM_BMU+i];
    }
}

// ---------------------------------------------------------------------------
// blocks 0..255: outs = fp32 copy of tgt; blocks 256..383: mask
__global__ __launch_bounds__(256) void k_misc(const float* __restrict__ tgt,
    const int* __restrict__ dur, float* __restrict__ dout)
{
    if (blockIdx.x < 256){
        int i = blockIdx.x*256 + threadIdx.x;
        ((float4*)dout)[i] = ((const float4*)tgt)[i];
    } else {
        __shared__ int red[256];
        int b = blockIdx.x - 256;
        int c = 0;
        for (int s = threadIdx.x; s < S_; s += 256) c += (dur[b*S_ + s] > 0) ? 1 : 0;
        red[threadIdx.x] = c;
        __syncthreads();
        for (int off=128; off>0; off>>=1){
            if (threadIdx.x < off) red[threadIdx.x] += red[threadIdx.x+off];
            __syncthreads();
        }
        int snt = red[0];
        for (int s = threadIdx.x; s < S_; s += 256)
            dout[OFF_MASK + (size_t)b*S_ + s] = (s >= snt) ? 1.f : 0.f;
    }
}

// ---------------------------------------------------------------------------
extern "C" void kernel_launch(void* const* d_in, const int* in_sizes, int n_in,
                              void* d_out, int out_size, void* d_ws, size_t ws_size,
                              hipStream_t stream)
{
    (void)d_ws; (void)ws_size;
    const float* enc  = (const float*)d_in[0];
    const float* tgt  = (const float*)d_in[1];
    const int*   dur  = (const int*)  d_in[2];
    const float* Wpre = (const float*)d_in[3];
    const float* bpre = (const float*)d_in[4];
    const float* Wih0 = (const float*)d_in[5];
    const float* Whh0 = (const float*)d_in[6];
    const float* bih0 = (const float*)d_in[7];
    const float* bhh0 = (const float*)d_in[8];
    const float* Wih1 = (const float*)d_in[9];
    const float* Whh1 = (const float*)d_in[10];
    const float* bih1 = (const float*)d_in[11];
    const float* bhh1 = (const float*)d_in[12];
    const float* Wpi  = (const float*)d_in[13];
    const float* bpi  = (const float*)d_in[14];
    const float* Wsig = (const float*)d_in[15];
    const float* bsig = (const float*)d_in[16];
    const float* Wmu  = (const float*)d_in[17];
    const float* bmu  = (const float*)d_in[18];
    float* dout = (float*)d_out;

    hipLaunchKernelGGL(k_ingest, dim3(4313), dim3(256), 0, stream,
                       Wih0, Whh0, Wih1, Whh1, Wpi, Wsig, Wmu,
                       Wpre, bpre, bih0, bhh0, bih1, bhh1, bpi, bsig, bmu, tgt);
    hipLaunchKernelGGL(k_gi0,  dim3(256),  dim3(256), 0, stream, enc);
    hipLaunchKernelGGL(k_rec,  dim3(32),   dim3(512), 0, stream, 0);
    hipLaunchKernelGGL(k_gi1,  dim3(256),  dim3(256), 0, stream);
    hipLaunchKernelGGL(k_rec,  dim3(32),   dim3(512), 0, stream, 1);
    hipLaunchKernelGGL(k_proj, dim3(512),  dim3(256), 0, stream, enc, dout);
    hipLaunchKernelGGL(k_misc, dim3(384),  dim3(256), 0, stream, tgt, dur, dout);
}